// Round 2
// baseline (3597.948 us; speedup 1.0000x reference)
//
#include <hip/hip_runtime.h>
#include <hip/hip_bf16.h>
#include <math.h>

#define BSZ 2
#define SEQ 1024
#define DM  1024          // d_model
#define DI  2048          // d_inner
#define DS  16            // d_state
#define DC  4             // d_conv
#define DR  64            // dt_rank
#define NDBL 96           // DR + 2*DS

typedef __hip_bfloat16 bf16;

__device__ __forceinline__ float ldf(const float* p, size_t i) { return p[i]; }
__device__ __forceinline__ float ldf(const bf16* p, size_t i)  { return __bfloat162float(p[i]); }
__device__ __forceinline__ void  stf(float* p, size_t i, float v) { p[i] = v; }
__device__ __forceinline__ void  stf(bf16* p, size_t i, float v)  { p[i] = __float2bfloat16(v); }

__device__ __forceinline__ float softplus_f(float x) {
    return (x > 0.f) ? (x + log1pf(expf(-x))) : log1pf(expf(x));
}

// C[M,N] = act(A[M,K] @ W[N,K]^T + bias), optional output-row flip within each
// batch's SEQ rows. A row-major stride lda, W row-major stride K (weights),
// C row-major stride ldc. 64x64 tile, BK=16, 256 threads, 4x4 per thread.
template <typename TA, typename TW, typename TC, int ACT, bool FLIP>
__global__ __launch_bounds__(256) void gemm_kernel(
    const TA* __restrict__ A, int lda,
    const TW* __restrict__ W,
    const TW* __restrict__ bias,
    TC* __restrict__ C, int ldc,
    int M, int N, int K)
{
    __shared__ float As[16][65];
    __shared__ float Ws[16][65];
    const int tid = threadIdx.x;
    const int tx = tid & 15;
    const int ty = tid >> 4;
    const int m0 = blockIdx.y * 64;
    const int n0 = blockIdx.x * 64;

    float acc[4][4] = {};

    const int lm = tid >> 2;        // 0..63 (row within tile for loads)
    const int lk = (tid & 3) * 4;   // 0,4,8,12

    for (int k0 = 0; k0 < K; k0 += 16) {
        {
            int gm = m0 + lm;
            #pragma unroll
            for (int i = 0; i < 4; i++) {
                int gk = k0 + lk + i;
                float v = 0.f;
                if (gm < M) v = ldf(A, (size_t)gm * lda + gk);
                As[lk + i][lm] = v;
            }
            int gn = n0 + lm;
            #pragma unroll
            for (int i = 0; i < 4; i++) {
                int gk = k0 + lk + i;
                float v = 0.f;
                if (gn < N) v = ldf(W, (size_t)gn * K + gk);
                Ws[lk + i][lm] = v;
            }
        }
        __syncthreads();
        #pragma unroll
        for (int k = 0; k < 16; k++) {
            float a[4], w[4];
            #pragma unroll
            for (int i = 0; i < 4; i++) a[i] = As[k][ty * 4 + i];
            #pragma unroll
            for (int j = 0; j < 4; j++) w[j] = Ws[k][tx * 4 + j];
            #pragma unroll
            for (int i = 0; i < 4; i++)
                #pragma unroll
                for (int j = 0; j < 4; j++) acc[i][j] += a[i] * w[j];
        }
        __syncthreads();
    }

    #pragma unroll
    for (int i = 0; i < 4; i++) {
        int gm = m0 + ty * 4 + i;
        if (gm >= M) continue;
        int om = gm;
        if (FLIP) {
            int b = gm / SEQ, l = gm % SEQ;
            om = b * SEQ + (SEQ - 1 - l);
        }
        #pragma unroll
        for (int j = 0; j < 4; j++) {
            int gn = n0 + tx * 4 + j;
            if (gn >= N) continue;
            float v = acc[i][j];
            if (ACT == 1) v = softplus_f(v + ldf(bias, gn));
            stf(C, (size_t)om * ldc + gn, v);
        }
    }
}

// xc[b,l,e] = silu(conv_b[e] + sum_k conv_w[e,k] * xi[b, l+k-3, e]); xi = xz[:, :DI]
__global__ __launch_bounds__(256) void conv_silu_kernel(
    const float* __restrict__ xz, const float* __restrict__ conv_w,
    const float* __restrict__ conv_b, float* __restrict__ xc)
{
    int idx = blockIdx.x * 256 + threadIdx.x;
    if (idx >= BSZ * SEQ * DI) return;
    int e = idx & (DI - 1);
    int bl = idx / DI;
    int l = bl & (SEQ - 1);
    float acc = conv_b[e];
    #pragma unroll
    for (int k = 0; k < DC; k++) {
        int ll = l + k - (DC - 1);
        if (ll >= 0)
            acc += conv_w[e * DC + k] * xz[((size_t)(bl - l + ll)) * (2 * DI) + e];
    }
    acc = acc / (1.f + expf(-acc));   // silu
    xc[idx] = acc;
}

// Sequential SSM scan. One thread per (b, e, n). 16-lane reduction for y.
// Reads delta from delta_y, writes gated y back in place.
__global__ __launch_bounds__(256) void scan_kernel(
    const float* __restrict__ dbl,   // (B*L, 96): dt | B | C
    const float* __restrict__ xc,    // (B*L, DI)
    const float* __restrict__ xz,    // (B*L, 2*DI)  (z = cols [DI, 2*DI))
    float* __restrict__ delta_y,     // in: delta, out: y  (B*L, DI)
    const float* __restrict__ A_log, // (DI, DS)
    const float* __restrict__ Dp)    // (DI,)
{
    const int tid = threadIdx.x;
    const int n = tid & 15;
    const int eg = tid >> 4;                         // 0..15
    const int b = blockIdx.x >> 7;                   // grid = 256
    const int e = ((blockIdx.x & 127) << 4) + eg;    // 0..2047

    const float Aen = -expf(A_log[e * DS + n]);
    const float Dv  = Dp[e];

    float h = 0.f;
    for (int t = 0; t < SEQ; t++) {
        size_t row = (size_t)(b * SEQ + t);
        float dv = delta_y[row * DI + e];
        float xv = xc[row * DI + e];
        float Bv = dbl[row * NDBL + DR + n];
        float Cv = dbl[row * NDBL + DR + DS + n];
        h = expf(dv * Aen) * h + (dv * xv) * Bv;
        float p = h * Cv;
        p += __shfl_xor(p, 1, 64);
        p += __shfl_xor(p, 2, 64);
        p += __shfl_xor(p, 4, 64);
        p += __shfl_xor(p, 8, 64);
        if (n == 0) {
            float zv = xz[row * (2 * DI) + DI + e];
            float y = (p + xv * Dv) * (zv / (1.f + expf(-zv)));
            delta_y[row * DI + e] = y;
        }
    }
}

extern "C" void kernel_launch(void* const* d_in, const int* in_sizes, int n_in,
                              void* d_out, int out_size, void* d_ws, size_t ws_size,
                              hipStream_t stream)
{
    const float* x = (const float*)d_in[0];
    const float* merge_w = (const float*)d_in[19];
    float* out = (float*)d_out;

    const int M = BSZ * SEQ;   // 2048

    float* ws = (float*)d_ws;
    float* ws_xz    = ws;                                  // M * 2*DI
    float* ws_xc    = ws_xz    + (size_t)M * 2 * DI;       // M * DI
    float* ws_dbl   = ws_xc    + (size_t)M * DI;           // M * 96
    float* ws_delta = ws_dbl   + (size_t)M * NDBL;         // M * DI (delta -> y)
    float* ws_cat   = ws_delta + (size_t)M * DI;           // M * 2*DM

    for (int dir = 0; dir < 2; dir++) {
        const float* in_proj  = (const float*)d_in[1 + 9 * dir + 0];
        const float* conv_w   = (const float*)d_in[1 + 9 * dir + 1];
        const float* conv_b   = (const float*)d_in[1 + 9 * dir + 2];
        const float* x_proj   = (const float*)d_in[1 + 9 * dir + 3];
        const float* dt_w     = (const float*)d_in[1 + 9 * dir + 4];
        const float* dt_b     = (const float*)d_in[1 + 9 * dir + 5];
        const float* A_log    = (const float*)d_in[1 + 9 * dir + 6];
        const float* Dp       = (const float*)d_in[1 + 9 * dir + 7];
        const float* out_proj = (const float*)d_in[1 + 9 * dir + 8];

        // 1) xz = x @ in_proj^T  (bwd: row-flipped output == in-proj of flipped x)
        {
            dim3 grid((2 * DI) / 64, M / 64);
            if (dir == 0)
                gemm_kernel<float, float, float, 0, false><<<grid, 256, 0, stream>>>(
                    x, DM, in_proj, nullptr, ws_xz, 2 * DI, M, 2 * DI, DM);
            else
                gemm_kernel<float, float, float, 0, true><<<grid, 256, 0, stream>>>(
                    x, DM, in_proj, nullptr, ws_xz, 2 * DI, M, 2 * DI, DM);
        }

        // 2) depthwise causal conv + silu
        conv_silu_kernel<<<(M * DI) / 256, 256, 0, stream>>>(ws_xz, conv_w, conv_b, ws_xc);

        // 3) dbl = xc @ x_proj^T   (N=96)
        {
            dim3 grid((NDBL + 63) / 64, M / 64);
            gemm_kernel<float, float, float, 0, false><<<grid, 256, 0, stream>>>(
                ws_xc, DI, x_proj, nullptr, ws_dbl, NDBL, M, NDBL, DI);
        }

        // 4) delta = softplus(dt @ dt_w^T + dt_b)
        {
            dim3 grid(DI / 64, M / 64);
            gemm_kernel<float, float, float, 1, false><<<grid, 256, 0, stream>>>(
                ws_dbl, NDBL, dt_w, dt_b, ws_delta, DI, M, DI, DR);
        }

        // 5) scan + skip + gate (y written over delta)
        scan_kernel<<<BSZ * (DI / 16), 256, 0, stream>>>(
            ws_dbl, ws_xc, ws_xz, ws_delta, A_log, Dp);

        // 6) dir_out = y @ out_proj^T -> cat columns [dir*DM, dir*DM+DM)
        {
            dim3 grid(DM / 64, M / 64);
            if (dir == 0)
                gemm_kernel<float, float, float, 0, false><<<grid, 256, 0, stream>>>(
                    ws_delta, DI, out_proj, nullptr, ws_cat, 2 * DM, M, DM, DI);
            else
                gemm_kernel<float, float, float, 0, true><<<grid, 256, 0, stream>>>(
                    ws_delta, DI, out_proj, nullptr, ws_cat + DM, 2 * DM, M, DM, DI);
        }
    }

    // 7) out = cat @ merge_w^T  (fp32 store)
    {
        dim3 grid(DM / 64, M / 64);
        gemm_kernel<float, float, float, 0, false><<<grid, 256, 0, stream>>>(
            ws_cat, 2 * DM, merge_w, nullptr, out, DM, M, DM, 2 * DM);
    }
}

// Round 3
// 2339.998 us; speedup vs baseline: 1.5376x; 1.5376x over previous
//
#include <hip/hip_runtime.h>
#include <hip/hip_bf16.h>
#include <math.h>

#define BSZ 2
#define SEQ 1024
#define DM  1024          // d_model
#define DI  2048          // d_inner
#define DS  16            // d_state
#define DC  4             // d_conv
#define DR  64            // dt_rank
#define NDBL 96           // DR + 2*DS
#define NC  32            // scan chunks
#define LC  32            // SEQ / NC

typedef __hip_bfloat16 bf16;

__device__ __forceinline__ float ldf(const float* p, size_t i) { return p[i]; }
__device__ __forceinline__ float ldf(const bf16* p, size_t i)  { return __bfloat162float(p[i]); }
__device__ __forceinline__ void  stf(float* p, size_t i, float v) { p[i] = v; }
__device__ __forceinline__ void  stf(bf16* p, size_t i, float v)  { p[i] = __float2bfloat16(v); }

__device__ __forceinline__ float softplus_f(float x) {
    return (x > 0.f) ? (x + log1pf(expf(-x))) : log1pf(expf(x));
}

// C[M,N] = act(A[M,K] @ W[N,K]^T + bias), optional output-row flip within each
// batch's SEQ rows. 64x64 tile, BK=16, 256 threads, 4x4 per thread.
template <typename TA, typename TW, typename TC, int ACT, bool FLIP>
__global__ __launch_bounds__(256) void gemm_kernel(
    const TA* __restrict__ A, int lda,
    const TW* __restrict__ W,
    const TW* __restrict__ bias,
    TC* __restrict__ C, int ldc,
    int M, int N, int K)
{
    __shared__ float As[16][65];
    __shared__ float Ws[16][65];
    const int tid = threadIdx.x;
    const int tx = tid & 15;
    const int ty = tid >> 4;
    const int m0 = blockIdx.y * 64;
    const int n0 = blockIdx.x * 64;

    float acc[4][4] = {};

    const int lm = tid >> 2;        // 0..63
    const int lk = (tid & 3) * 4;   // 0,4,8,12

    for (int k0 = 0; k0 < K; k0 += 16) {
        {
            int gm = m0 + lm;
            #pragma unroll
            for (int i = 0; i < 4; i++) {
                int gk = k0 + lk + i;
                float v = 0.f;
                if (gm < M) v = ldf(A, (size_t)gm * lda + gk);
                As[lk + i][lm] = v;
            }
            int gn = n0 + lm;
            #pragma unroll
            for (int i = 0; i < 4; i++) {
                int gk = k0 + lk + i;
                float v = 0.f;
                if (gn < N) v = ldf(W, (size_t)gn * K + gk);
                Ws[lk + i][lm] = v;
            }
        }
        __syncthreads();
        #pragma unroll
        for (int k = 0; k < 16; k++) {
            float a[4], w[4];
            #pragma unroll
            for (int i = 0; i < 4; i++) a[i] = As[k][ty * 4 + i];
            #pragma unroll
            for (int j = 0; j < 4; j++) w[j] = Ws[k][tx * 4 + j];
            #pragma unroll
            for (int i = 0; i < 4; i++)
                #pragma unroll
                for (int j = 0; j < 4; j++) acc[i][j] += a[i] * w[j];
        }
        __syncthreads();
    }

    #pragma unroll
    for (int i = 0; i < 4; i++) {
        int gm = m0 + ty * 4 + i;
        if (gm >= M) continue;
        int om = gm;
        if (FLIP) {
            int b = gm / SEQ, l = gm % SEQ;
            om = b * SEQ + (SEQ - 1 - l);
        }
        #pragma unroll
        for (int j = 0; j < 4; j++) {
            int gn = n0 + tx * 4 + j;
            if (gn >= N) continue;
            float v = acc[i][j];
            if (ACT == 1) v = softplus_f(v + ldf(bias, gn));
            stf(C, (size_t)om * ldc + gn, v);
        }
    }
}

// xc[b,l,e] = silu(conv_b[e] + sum_k conv_w[e,k] * xi[b, l+k-3, e]); xi = xz[:, :DI]
__global__ __launch_bounds__(256) void conv_silu_kernel(
    const float* __restrict__ xz, const float* __restrict__ conv_w,
    const float* __restrict__ conv_b, float* __restrict__ xc)
{
    int idx = blockIdx.x * 256 + threadIdx.x;
    if (idx >= BSZ * SEQ * DI) return;
    int e = idx & (DI - 1);
    int bl = idx / DI;
    int l = bl & (SEQ - 1);
    float acc = conv_b[e];
    #pragma unroll
    for (int k = 0; k < DC; k++) {
        int ll = l + k - (DC - 1);
        if (ll >= 0)
            acc += conv_w[e * DC + k] * xz[((size_t)(bl - l + ll)) * (2 * DI) + e];
    }
    acc = acc / (1.f + expf(-acc));   // silu
    xc[idx] = acc;
}

// ---- Chunked scan: h_{t+1} = dA_t h_t + dBu_t composes affinely over chunks.

// Pass 1: per-(b,e,n,chunk) compute P = prod dA, q = local scan.
// grid: (NC, DI/16, BSZ), block 256 = 16e x 16n.
__global__ __launch_bounds__(256) void scan_pass1(
    const float* __restrict__ dbl,    // (B*L, 96)
    const float* __restrict__ xc,     // (B*L, DI)
    const float* __restrict__ delta,  // (B*L, DI)
    const float* __restrict__ A_log,  // (DI, DS)
    float* __restrict__ Pout,         // (B, NC, DI, DS)
    float* __restrict__ Qout)
{
    const int tid = threadIdx.x;
    const int n = tid & 15;
    const int eg = tid >> 4;
    const int c = blockIdx.x;
    const int e = blockIdx.y * 16 + eg;
    const int b = blockIdx.z;

    const float Aen = -expf(A_log[e * DS + n]);
    float P = 1.f, q = 0.f;
    const int row0 = b * SEQ + c * LC;
    #pragma unroll 4
    for (int i = 0; i < LC; i++) {
        size_t row = (size_t)(row0 + i);
        float dv = delta[row * DI + e];
        float xv = xc[row * DI + e];
        float Bv = dbl[row * NDBL + DR + n];
        float dA = expf(dv * Aen);
        P *= dA;
        q = dA * q + (dv * xv) * Bv;
    }
    size_t idx = ((size_t)(b * NC + c) * DI + e) * DS + n;
    Pout[idx] = P;
    Qout[idx] = q;
}

// Pass 2: serial scan of chunk summaries -> per-chunk initial state h0.
// grid: (B*DI*DS)/256 = 256 blocks.
__global__ __launch_bounds__(256) void scan_pass2(
    const float* __restrict__ P, const float* __restrict__ Q,
    float* __restrict__ H0)   // (B, NC, DI, DS)
{
    const int gid = blockIdx.x * 256 + threadIdx.x;  // = (b*DI + e)*DS + n
    const int en = gid & (DI * DS - 1);
    const int b = gid >> 15;
    float h = 0.f;
    for (int c = 0; c < NC; c++) {
        size_t idx = ((size_t)(b * NC + c) * DI * DS) + en;
        H0[idx] = h;
        h = P[idx] * h + Q[idx];
    }
}

// Pass 3: replay chunk from h0, emit gated y (overwrites delta buffer).
// grid: (NC, DI/16, BSZ), block 256.
__global__ __launch_bounds__(256) void scan_pass3(
    const float* __restrict__ dbl,
    const float* __restrict__ xc,
    const float* __restrict__ xz,      // z = cols [DI, 2*DI)
    float* __restrict__ delta_y,       // in: delta, out: y
    const float* __restrict__ A_log,
    const float* __restrict__ Dp,
    const float* __restrict__ H0)
{
    const int tid = threadIdx.x;
    const int n = tid & 15;
    const int eg = tid >> 4;
    const int c = blockIdx.x;
    const int e = blockIdx.y * 16 + eg;
    const int b = blockIdx.z;

    const float Aen = -expf(A_log[e * DS + n]);
    const float Dv  = Dp[e];
    float h = H0[((size_t)(b * NC + c) * DI + e) * DS + n];
    const int row0 = b * SEQ + c * LC;
    #pragma unroll 4
    for (int i = 0; i < LC; i++) {
        size_t row = (size_t)(row0 + i);
        float dv = delta_y[row * DI + e];
        float xv = xc[row * DI + e];
        float Bv = dbl[row * NDBL + DR + n];
        float Cv = dbl[row * NDBL + DR + DS + n];
        h = expf(dv * Aen) * h + (dv * xv) * Bv;
        float p = h * Cv;
        p += __shfl_xor(p, 1, 64);
        p += __shfl_xor(p, 2, 64);
        p += __shfl_xor(p, 4, 64);
        p += __shfl_xor(p, 8, 64);
        if (n == 0) {
            float zv = xz[row * (2 * DI) + DI + e];
            float y = (p + xv * Dv) * (zv / (1.f + expf(-zv)));
            delta_y[row * DI + e] = y;
        }
    }
}

extern "C" void kernel_launch(void* const* d_in, const int* in_sizes, int n_in,
                              void* d_out, int out_size, void* d_ws, size_t ws_size,
                              hipStream_t stream)
{
    const float* x = (const float*)d_in[0];
    const float* merge_w = (const float*)d_in[19];
    float* out = (float*)d_out;

    const int M = BSZ * SEQ;   // 2048

    float* ws = (float*)d_ws;
    float* ws_xz    = ws;                                  // M * 2*DI
    float* ws_xc    = ws_xz    + (size_t)M * 2 * DI;       // M * DI
    float* ws_dbl   = ws_xc    + (size_t)M * DI;           // M * 96
    float* ws_delta = ws_dbl   + (size_t)M * NDBL;         // M * DI (delta -> y)
    float* ws_cat   = ws_delta + (size_t)M * DI;           // M * 2*DM
    float* ws_P     = ws_cat   + (size_t)M * 2 * DM;       // B*NC*DI*DS = 2M
    float* ws_Q     = ws_P     + (size_t)BSZ * NC * DI * DS;
    float* ws_H0    = ws_Q     + (size_t)BSZ * NC * DI * DS;

    for (int dir = 0; dir < 2; dir++) {
        const float* in_proj  = (const float*)d_in[1 + 9 * dir + 0];
        const float* conv_w   = (const float*)d_in[1 + 9 * dir + 1];
        const float* conv_b   = (const float*)d_in[1 + 9 * dir + 2];
        const float* x_proj   = (const float*)d_in[1 + 9 * dir + 3];
        const float* dt_w     = (const float*)d_in[1 + 9 * dir + 4];
        const float* dt_b     = (const float*)d_in[1 + 9 * dir + 5];
        const float* A_log    = (const float*)d_in[1 + 9 * dir + 6];
        const float* Dp       = (const float*)d_in[1 + 9 * dir + 7];
        const float* out_proj = (const float*)d_in[1 + 9 * dir + 8];

        // 1) xz = x @ in_proj^T  (bwd: row-flipped output == in-proj of flipped x)
        {
            dim3 grid((2 * DI) / 64, M / 64);
            if (dir == 0)
                gemm_kernel<float, float, float, 0, false><<<grid, 256, 0, stream>>>(
                    x, DM, in_proj, nullptr, ws_xz, 2 * DI, M, 2 * DI, DM);
            else
                gemm_kernel<float, float, float, 0, true><<<grid, 256, 0, stream>>>(
                    x, DM, in_proj, nullptr, ws_xz, 2 * DI, M, 2 * DI, DM);
        }

        // 2) depthwise causal conv + silu
        conv_silu_kernel<<<(M * DI) / 256, 256, 0, stream>>>(ws_xz, conv_w, conv_b, ws_xc);

        // 3) dbl = xc @ x_proj^T   (N=96)
        {
            dim3 grid((NDBL + 63) / 64, M / 64);
            gemm_kernel<float, float, float, 0, false><<<grid, 256, 0, stream>>>(
                ws_xc, DI, x_proj, nullptr, ws_dbl, NDBL, M, NDBL, DI);
        }

        // 4) delta = softplus(dt @ dt_w^T + dt_b)
        {
            dim3 grid(DI / 64, M / 64);
            gemm_kernel<float, float, float, 1, false><<<grid, 256, 0, stream>>>(
                ws_dbl, NDBL, dt_w, dt_b, ws_delta, DI, M, DI, DR);
        }

        // 5) chunked scan + skip + gate (y over delta)
        {
            dim3 grid(NC, DI / 16, BSZ);
            scan_pass1<<<grid, 256, 0, stream>>>(ws_dbl, ws_xc, ws_delta, A_log, ws_P, ws_Q);
            scan_pass2<<<(BSZ * DI * DS) / 256, 256, 0, stream>>>(ws_P, ws_Q, ws_H0);
            scan_pass3<<<grid, 256, 0, stream>>>(ws_dbl, ws_xc, ws_xz, ws_delta, A_log, Dp, ws_H0);
        }

        // 6) dir_out = y @ out_proj^T -> cat columns [dir*DM, dir*DM+DM)
        {
            dim3 grid(DM / 64, M / 64);
            if (dir == 0)
                gemm_kernel<float, float, float, 0, false><<<grid, 256, 0, stream>>>(
                    ws_delta, DI, out_proj, nullptr, ws_cat, 2 * DM, M, DM, DI);
            else
                gemm_kernel<float, float, float, 0, true><<<grid, 256, 0, stream>>>(
                    ws_delta, DI, out_proj, nullptr, ws_cat + DM, 2 * DM, M, DM, DI);
        }
    }

    // 7) out = cat @ merge_w^T  (fp32 store)
    {
        dim3 grid(DM / 64, M / 64);
        gemm_kernel<float, float, float, 0, false><<<grid, 256, 0, stream>>>(
            ws_cat, 2 * DM, merge_w, nullptr, out, DM, M, DM, 2 * DM);
    }
}

// Round 4
// 966.114 us; speedup vs baseline: 3.7241x; 2.4221x over previous
//
#include <hip/hip_runtime.h>
#include <math.h>

#define BSZ 2
#define SEQ 1024
#define DM  1024          // d_model
#define DI  2048          // d_inner
#define DS  16            // d_state
#define DC  4             // d_conv
#define DR  64            // dt_rank
#define NDBL 96           // DR + 2*DS
#define NC  32            // scan chunks
#define LC  32            // SEQ / NC

typedef unsigned short u16;
typedef __bf16 bf16x8 __attribute__((ext_vector_type(8)));
typedef float  f32x4  __attribute__((ext_vector_type(4)));

__device__ __forceinline__ u16 f2b(float f) {
    unsigned int u = __float_as_uint(f);
    unsigned int r = (u + 0x7fffu + ((u >> 16) & 1u)) >> 16;
    return (u16)r;
}
__device__ __forceinline__ float b2f(u16 h) {
    return __uint_as_float(((unsigned int)h) << 16);
}

__device__ __forceinline__ float ldf(const float* p, size_t i) { return p[i]; }
__device__ __forceinline__ float ldf(const u16* p, size_t i)   { return b2f(p[i]); }
__device__ __forceinline__ void  stf(float* p, size_t i, float v) { p[i] = v; }
__device__ __forceinline__ void  stf(u16* p, size_t i, float v)   { p[i] = f2b(v); }

__device__ __forceinline__ float softplus_f(float x) {
    return (x > 0.f) ? (x + log1pf(expf(-x))) : log1pf(expf(x));
}

// fp32 -> bf16 pack, 4 elems/thread. n must be multiple of 4.
__global__ __launch_bounds__(256) void cvt_f2b_kernel(
    const float* __restrict__ in, u16* __restrict__ out, int n4)
{
    int i = blockIdx.x * 256 + threadIdx.x;
    if (i >= n4) return;
    float4 v = ((const float4*)in)[i];
    ushort4 o;
    o.x = f2b(v.x); o.y = f2b(v.y); o.z = f2b(v.z); o.w = f2b(v.w);
    ((ushort4*)out)[i] = o;
}

// ---------------- MFMA GEMM: C[M,N] = A[M,K] @ W[N,K]^T ----------------
// A,W bf16 row-major (stride K). 128x128 tile, BK=32, 256 threads = 4 waves
// (2x2 of 64x64), each wave 4x4 of 16x16x32 MFMA. Optional per-batch row flip.
// A-tile rows always in-bounds (M multiple of 128 here); W rows guarded (N=96 case).
template <typename TC, bool FLIP>
__global__ __launch_bounds__(256) void mfma_gemm(
    const u16* __restrict__ A,
    const u16* __restrict__ W,
    TC* __restrict__ C, int ldc,
    int M, int N, int K)
{
    __shared__ u16 As[128 * 32];
    __shared__ u16 Ws[128 * 32];

    const int t = threadIdx.x;
    const int wave = t >> 6;
    const int lane = t & 63;
    const int wm = (wave & 1) * 64;
    const int wn = (wave >> 1) * 64;
    const int fm = lane & 15;
    const int fk = (lane >> 4) * 8;
    const int m0 = blockIdx.y * 128;
    const int n0 = blockIdx.x * 128;

    f32x4 acc[4][4] = {};

    for (int k0 = 0; k0 < K; k0 += 32) {
        // stage 128x32 of A and W; 2 passes x 16B/lane each
        #pragma unroll
        for (int p = 0; p < 2; p++) {
            int elem = p * 256 + t;
            int r = elem >> 2;
            int c = (elem & 3) * 8;
            *(uint4*)&As[r * 32 + c] =
                *(const uint4*)(A + (size_t)(m0 + r) * K + k0 + c);
            uint4 wv = {0u, 0u, 0u, 0u};
            int gn = n0 + r;
            if (gn < N) wv = *(const uint4*)(W + (size_t)gn * K + k0 + c);
            *(uint4*)&Ws[r * 32 + c] = wv;
        }
        __syncthreads();

        bf16x8 af[4], wf[4];
        #pragma unroll
        for (int mi = 0; mi < 4; mi++)
            af[mi] = *(const bf16x8*)&As[(wm + mi * 16 + fm) * 32 + fk];
        #pragma unroll
        for (int ni = 0; ni < 4; ni++)
            wf[ni] = *(const bf16x8*)&Ws[(wn + ni * 16 + fm) * 32 + fk];
        #pragma unroll
        for (int mi = 0; mi < 4; mi++)
            #pragma unroll
            for (int ni = 0; ni < 4; ni++)
                acc[mi][ni] = __builtin_amdgcn_mfma_f32_16x16x32_bf16(
                    af[mi], wf[ni], acc[mi][ni], 0, 0, 0);
        __syncthreads();
    }

    // C/D layout: col = lane&15, row = (lane>>4)*4 + reg
    const int rb = (lane >> 4) * 4;
    const int cc = lane & 15;
    #pragma unroll
    for (int mi = 0; mi < 4; mi++) {
        #pragma unroll
        for (int r = 0; r < 4; r++) {
            int gm = m0 + wm + mi * 16 + rb + r;
            int om = gm;
            if (FLIP) {
                int b = gm / SEQ, l = gm % SEQ;
                om = b * SEQ + (SEQ - 1 - l);
            }
            #pragma unroll
            for (int ni = 0; ni < 4; ni++) {
                int gn = n0 + wn + ni * 16 + cc;
                if (gn < N) stf(C, (size_t)om * ldc + gn, acc[mi][ni][r]);
            }
        }
    }
}

// ---------------- fp32 vector GEMM (kept for dt: K=64) ----------------
template <typename TA, typename TW, typename TC, int ACT, bool FLIP>
__global__ __launch_bounds__(256) void gemm_kernel(
    const TA* __restrict__ A, int lda,
    const TW* __restrict__ W,
    const TW* __restrict__ bias,
    TC* __restrict__ C, int ldc,
    int M, int N, int K)
{
    __shared__ float As[16][65];
    __shared__ float Ws[16][65];
    const int tid = threadIdx.x;
    const int tx = tid & 15;
    const int ty = tid >> 4;
    const int m0 = blockIdx.y * 64;
    const int n0 = blockIdx.x * 64;

    float acc[4][4] = {};
    const int lm = tid >> 2;
    const int lk = (tid & 3) * 4;

    for (int k0 = 0; k0 < K; k0 += 16) {
        {
            int gm = m0 + lm;
            #pragma unroll
            for (int i = 0; i < 4; i++) {
                int gk = k0 + lk + i;
                float v = 0.f;
                if (gm < M) v = ldf(A, (size_t)gm * lda + gk);
                As[lk + i][lm] = v;
            }
            int gn = n0 + lm;
            #pragma unroll
            for (int i = 0; i < 4; i++) {
                int gk = k0 + lk + i;
                float v = 0.f;
                if (gn < N) v = ldf(W, (size_t)gn * K + gk);
                Ws[lk + i][lm] = v;
            }
        }
        __syncthreads();
        #pragma unroll
        for (int k = 0; k < 16; k++) {
            float a[4], w[4];
            #pragma unroll
            for (int i = 0; i < 4; i++) a[i] = As[k][ty * 4 + i];
            #pragma unroll
            for (int j = 0; j < 4; j++) w[j] = Ws[k][tx * 4 + j];
            #pragma unroll
            for (int i = 0; i < 4; i++)
                #pragma unroll
                for (int j = 0; j < 4; j++) acc[i][j] += a[i] * w[j];
        }
        __syncthreads();
    }

    #pragma unroll
    for (int i = 0; i < 4; i++) {
        int gm = m0 + ty * 4 + i;
        if (gm >= M) continue;
        int om = gm;
        if (FLIP) {
            int b = gm / SEQ, l = gm % SEQ;
            om = b * SEQ + (SEQ - 1 - l);
        }
        #pragma unroll
        for (int j = 0; j < 4; j++) {
            int gn = n0 + tx * 4 + j;
            if (gn >= N) continue;
            float v = acc[i][j];
            if (ACT == 1) v = softplus_f(v + ldf(bias, gn));
            stf(C, (size_t)om * ldc + gn, v);
        }
    }
}

// conv + silu; writes fp32 xc (for scan) and bf16 xcb (for x_proj MFMA)
__global__ __launch_bounds__(256) void conv_silu_kernel(
    const float* __restrict__ xz, const float* __restrict__ conv_w,
    const float* __restrict__ conv_b, float* __restrict__ xc,
    u16* __restrict__ xcb)
{
    int idx = blockIdx.x * 256 + threadIdx.x;
    if (idx >= BSZ * SEQ * DI) return;
    int e = idx & (DI - 1);
    int bl = idx / DI;
    int l = bl & (SEQ - 1);
    float acc = conv_b[e];
    #pragma unroll
    for (int k = 0; k < DC; k++) {
        int ll = l + k - (DC - 1);
        if (ll >= 0)
            acc += conv_w[e * DC + k] * xz[((size_t)(bl - l + ll)) * (2 * DI) + e];
    }
    acc = acc / (1.f + expf(-acc));   // silu
    xc[idx] = acc;
    xcb[idx] = f2b(acc);
}

// ---- Chunked scan ----
__global__ __launch_bounds__(256) void scan_pass1(
    const float* __restrict__ dbl,
    const float* __restrict__ xc,
    const u16*  __restrict__ delta,
    const float* __restrict__ A_log,
    float* __restrict__ Pout, float* __restrict__ Qout)
{
    const int tid = threadIdx.x;
    const int n = tid & 15;
    const int eg = tid >> 4;
    const int c = blockIdx.x;
    const int e = blockIdx.y * 16 + eg;
    const int b = blockIdx.z;

    const float Aen = -expf(A_log[e * DS + n]);
    float P = 1.f, q = 0.f;
    const int row0 = b * SEQ + c * LC;
    #pragma unroll 4
    for (int i = 0; i < LC; i++) {
        size_t row = (size_t)(row0 + i);
        float dv = b2f(delta[row * DI + e]);
        float xv = xc[row * DI + e];
        float Bv = dbl[row * NDBL + DR + n];
        float dA = expf(dv * Aen);
        P *= dA;
        q = dA * q + (dv * xv) * Bv;
    }
    size_t idx = ((size_t)(b * NC + c) * DI + e) * DS + n;
    Pout[idx] = P;
    Qout[idx] = q;
}

__global__ __launch_bounds__(256) void scan_pass2(
    const float* __restrict__ P, const float* __restrict__ Q,
    float* __restrict__ H0)
{
    const int gid = blockIdx.x * 256 + threadIdx.x;
    const int en = gid & (DI * DS - 1);
    const int b = gid >> 15;
    float h = 0.f;
    for (int c = 0; c < NC; c++) {
        size_t idx = ((size_t)(b * NC + c) * DI * DS) + en;
        H0[idx] = h;
        h = P[idx] * h + Q[idx];
    }
}

__global__ __launch_bounds__(256) void scan_pass3(
    const float* __restrict__ dbl,
    const float* __restrict__ xc,
    const float* __restrict__ xz,      // z = cols [DI, 2*DI)
    const u16*  __restrict__ delta,
    const float* __restrict__ A_log,
    const float* __restrict__ Dp,
    const float* __restrict__ H0,
    u16* __restrict__ ybf)             // output (bf16, feeds out_proj MFMA)
{
    const int tid = threadIdx.x;
    const int n = tid & 15;
    const int eg = tid >> 4;
    const int c = blockIdx.x;
    const int e = blockIdx.y * 16 + eg;
    const int b = blockIdx.z;

    const float Aen = -expf(A_log[e * DS + n]);
    const float Dv  = Dp[e];
    float h = H0[((size_t)(b * NC + c) * DI + e) * DS + n];
    const int row0 = b * SEQ + c * LC;
    #pragma unroll 4
    for (int i = 0; i < LC; i++) {
        size_t row = (size_t)(row0 + i);
        float dv = b2f(delta[row * DI + e]);
        float xv = xc[row * DI + e];
        float Bv = dbl[row * NDBL + DR + n];
        float Cv = dbl[row * NDBL + DR + DS + n];
        h = expf(dv * Aen) * h + (dv * xv) * Bv;
        float p = h * Cv;
        p += __shfl_xor(p, 1, 64);
        p += __shfl_xor(p, 2, 64);
        p += __shfl_xor(p, 4, 64);
        p += __shfl_xor(p, 8, 64);
        if (n == 0) {
            float zv = xz[row * (2 * DI) + DI + e];
            float y = (p + xv * Dv) * (zv / (1.f + expf(-zv)));
            ybf[row * DI + e] = f2b(y);
        }
    }
}

static inline void cvt(const float* in, u16* out, int n, hipStream_t s) {
    int n4 = n / 4;
    cvt_f2b_kernel<<<(n4 + 255) / 256, 256, 0, s>>>(in, out, n4);
}

extern "C" void kernel_launch(void* const* d_in, const int* in_sizes, int n_in,
                              void* d_out, int out_size, void* d_ws, size_t ws_size,
                              hipStream_t stream)
{
    const float* x = (const float*)d_in[0];
    const float* merge_w = (const float*)d_in[19];
    float* out = (float*)d_out;

    const int M = BSZ * SEQ;   // 2048

    // workspace layout (float units); xcb aliases Q, ybf aliases P
    float* ws = (float*)d_ws;
    float* ws_xz  = ws;                                   // 8,388,608 f
    float* ws_xc  = ws_xz  + (size_t)M * 2 * DI;          // 4,194,304 f
    float* ws_dbl = ws_xc  + (size_t)M * DI;              //   196,608 f
    float* ws_P   = ws_dbl + (size_t)M * NDBL;            // 2,097,152 f
    float* ws_Q   = ws_P   + (size_t)BSZ * NC * DI * DS;  // 2,097,152 f
    float* ws_H0  = ws_Q   + (size_t)BSZ * NC * DI * DS;  // 2,097,152 f
    u16* ws_delta = (u16*)(ws_H0 + (size_t)BSZ * NC * DI * DS);  // M*DI u16
    u16* ws_cat   = ws_delta + (size_t)M * DI;            // M*2DM u16
    u16* ws_xbf   = ws_cat   + (size_t)M * 2 * DM;        // M*DM u16
    u16* ws_wbf   = ws_xbf   + (size_t)M * DM;            // 4,194,304 u16 (shared weights)
    u16* ws_xcb   = (u16*)ws_Q;                           // alias: dead before pass1 writes Q
    u16* ws_ybf   = (u16*)ws_P;                           // alias: dead before pass3 writes ybf

    cvt(x, ws_xbf, M * DM, stream);

    for (int dir = 0; dir < 2; dir++) {
        const float* in_proj  = (const float*)d_in[1 + 9 * dir + 0];
        const float* conv_w   = (const float*)d_in[1 + 9 * dir + 1];
        const float* conv_b   = (const float*)d_in[1 + 9 * dir + 2];
        const float* x_proj   = (const float*)d_in[1 + 9 * dir + 3];
        const float* dt_w     = (const float*)d_in[1 + 9 * dir + 4];
        const float* dt_b     = (const float*)d_in[1 + 9 * dir + 5];
        const float* A_log    = (const float*)d_in[1 + 9 * dir + 6];
        const float* Dp       = (const float*)d_in[1 + 9 * dir + 7];
        const float* out_proj = (const float*)d_in[1 + 9 * dir + 8];

        // 1) xz = x @ in_proj^T (bwd: flip output rows)
        cvt(in_proj, ws_wbf, 2 * DI * DM, stream);
        {
            dim3 grid((2 * DI) / 128, M / 128);
            if (dir == 0)
                mfma_gemm<float, false><<<grid, 256, 0, stream>>>(
                    ws_xbf, ws_wbf, ws_xz, 2 * DI, M, 2 * DI, DM);
            else
                mfma_gemm<float, true><<<grid, 256, 0, stream>>>(
                    ws_xbf, ws_wbf, ws_xz, 2 * DI, M, 2 * DI, DM);
        }

        // 2) conv + silu
        conv_silu_kernel<<<(M * DI) / 256, 256, 0, stream>>>(
            ws_xz, conv_w, conv_b, ws_xc, ws_xcb);

        // 3) dbl = xc @ x_proj^T  (N=96, guarded)
        cvt(x_proj, ws_wbf, NDBL * DI, stream);
        {
            dim3 grid(1, M / 128);
            mfma_gemm<float, false><<<grid, 256, 0, stream>>>(
                ws_xcb, ws_wbf, ws_dbl, NDBL, M, NDBL, DI);
        }

        // 4) delta = softplus(dt @ dt_w^T + dt_b)  -> bf16 (vector GEMM, K=64)
        {
            dim3 grid(DI / 64, M / 64);
            gemm_kernel<float, float, u16, 1, false><<<grid, 256, 0, stream>>>(
                ws_dbl, NDBL, dt_w, dt_b, ws_delta, DI, M, DI, DR);
        }

        // 5) chunked scan
        {
            dim3 grid(NC, DI / 16, BSZ);
            scan_pass1<<<grid, 256, 0, stream>>>(ws_dbl, ws_xc, ws_delta, A_log, ws_P, ws_Q);
            scan_pass2<<<(BSZ * DI * DS) / 256, 256, 0, stream>>>(ws_P, ws_Q, ws_H0);
            scan_pass3<<<grid, 256, 0, stream>>>(ws_dbl, ws_xc, ws_xz, ws_delta,
                                                 A_log, Dp, ws_H0, ws_ybf);
        }

        // 6) cat[:, dir*DM:+DM] = y @ out_proj^T (bwd: flip rows back)
        cvt(out_proj, ws_wbf, DM * DI, stream);
        {
            dim3 grid(DM / 128, M / 128);
            if (dir == 0)
                mfma_gemm<u16, false><<<grid, 256, 0, stream>>>(
                    ws_ybf, ws_wbf, ws_cat, 2 * DM, M, DM, DI);
            else
                mfma_gemm<u16, true><<<grid, 256, 0, stream>>>(
                    ws_ybf, ws_wbf, ws_cat + DM, 2 * DM, M, DM, DI);
        }
    }

    // 7) out = cat @ merge_w^T (fp32 out)
    cvt(merge_w, ws_wbf, DM * 2 * DM, stream);
    {
        dim3 grid(DM / 128, M / 128);
        mfma_gemm<float, false><<<grid, 256, 0, stream>>>(
            ws_cat, ws_wbf, out, DM, M, DM, 2 * DM);
    }
}

// Round 5
// 930.687 us; speedup vs baseline: 3.8659x; 1.0381x over previous
//
#include <hip/hip_runtime.h>
#include <math.h>

#define BSZ 2
#define SEQ 1024
#define DM  1024          // d_model
#define DI  2048          // d_inner
#define DS  16            // d_state
#define DC  4             // d_conv
#define DR  64            // dt_rank
#define NDBL 96           // DR + 2*DS
#define NC  32            // scan chunks
#define LC  32            // SEQ / NC

typedef unsigned short u16;
typedef __bf16 bf16x8 __attribute__((ext_vector_type(8)));
typedef float  f32x4  __attribute__((ext_vector_type(4)));

__device__ __forceinline__ u16 f2b(float f) {
    unsigned int u = __float_as_uint(f);
    unsigned int r = (u + 0x7fffu + ((u >> 16) & 1u)) >> 16;
    return (u16)r;
}
__device__ __forceinline__ float b2f(u16 h) {
    return __uint_as_float(((unsigned int)h) << 16);
}

__device__ __forceinline__ float ldf(const float* p, size_t i) { return p[i]; }
__device__ __forceinline__ float ldf(const u16* p, size_t i)   { return b2f(p[i]); }
__device__ __forceinline__ void  stf(float* p, size_t i, float v) { p[i] = v; }
__device__ __forceinline__ void  stf(u16* p, size_t i, float v)   { p[i] = f2b(v); }

// ---- fast transcendentals: native v_exp_f32 / v_log_f32 / v_rcp_f32 ----
__device__ __forceinline__ float fexp(float x)  { return __expf(x); }
__device__ __forceinline__ float frcp(float x)  { return __builtin_amdgcn_rcpf(x); }
__device__ __forceinline__ float silu_fast(float x) {
    return x * frcp(1.f + fexp(-x));
}
__device__ __forceinline__ float softplus_fast(float x) {
    // safe: for x<=15, 1+e^x has no overflow; v_log is ~1ulp
    return (x > 15.f) ? x : __logf(1.f + fexp(x));
}

// fp32 -> bf16 pack, 4 elems/thread. n must be multiple of 4.
__global__ __launch_bounds__(256) void cvt_f2b_kernel(
    const float* __restrict__ in, u16* __restrict__ out, int n4)
{
    int i = blockIdx.x * 256 + threadIdx.x;
    if (i >= n4) return;
    float4 v = ((const float4*)in)[i];
    ushort4 o;
    o.x = f2b(v.x); o.y = f2b(v.y); o.z = f2b(v.z); o.w = f2b(v.w);
    ((ushort4*)out)[i] = o;
}

// ---------------- MFMA GEMM: C[M,N] = A[M,K] @ W[N,K]^T ----------------
// A,W bf16 row-major (stride K). 128x128 tile, BK=32, 256 threads = 4 waves
// (2x2 of 64x64), each wave 4x4 of 16x16x32 MFMA. Optional per-batch row flip.
template <typename TC, bool FLIP>
__global__ __launch_bounds__(256) void mfma_gemm(
    const u16* __restrict__ A,
    const u16* __restrict__ W,
    TC* __restrict__ C, int ldc,
    int M, int N, int K)
{
    __shared__ u16 As[128 * 32];
    __shared__ u16 Ws[128 * 32];

    const int t = threadIdx.x;
    const int wave = t >> 6;
    const int lane = t & 63;
    const int wm = (wave & 1) * 64;
    const int wn = (wave >> 1) * 64;
    const int fm = lane & 15;
    const int fk = (lane >> 4) * 8;
    const int m0 = blockIdx.y * 128;
    const int n0 = blockIdx.x * 128;

    f32x4 acc[4][4] = {};

    for (int k0 = 0; k0 < K; k0 += 32) {
        #pragma unroll
        for (int p = 0; p < 2; p++) {
            int elem = p * 256 + t;
            int r = elem >> 2;
            int c = (elem & 3) * 8;
            *(uint4*)&As[r * 32 + c] =
                *(const uint4*)(A + (size_t)(m0 + r) * K + k0 + c);
            uint4 wv = {0u, 0u, 0u, 0u};
            int gn = n0 + r;
            if (gn < N) wv = *(const uint4*)(W + (size_t)gn * K + k0 + c);
            *(uint4*)&Ws[r * 32 + c] = wv;
        }
        __syncthreads();

        bf16x8 af[4], wf[4];
        #pragma unroll
        for (int mi = 0; mi < 4; mi++)
            af[mi] = *(const bf16x8*)&As[(wm + mi * 16 + fm) * 32 + fk];
        #pragma unroll
        for (int ni = 0; ni < 4; ni++)
            wf[ni] = *(const bf16x8*)&Ws[(wn + ni * 16 + fm) * 32 + fk];
        #pragma unroll
        for (int mi = 0; mi < 4; mi++)
            #pragma unroll
            for (int ni = 0; ni < 4; ni++)
                acc[mi][ni] = __builtin_amdgcn_mfma_f32_16x16x32_bf16(
                    af[mi], wf[ni], acc[mi][ni], 0, 0, 0);
        __syncthreads();
    }

    const int rb = (lane >> 4) * 4;
    const int cc = lane & 15;
    #pragma unroll
    for (int mi = 0; mi < 4; mi++) {
        #pragma unroll
        for (int r = 0; r < 4; r++) {
            int gm = m0 + wm + mi * 16 + rb + r;
            int om = gm;
            if (FLIP) {
                int b = gm / SEQ, l = gm % SEQ;
                om = b * SEQ + (SEQ - 1 - l);
            }
            #pragma unroll
            for (int ni = 0; ni < 4; ni++) {
                int gn = n0 + wn + ni * 16 + cc;
                if (gn < N) stf(C, (size_t)om * ldc + gn, acc[mi][ni][r]);
            }
        }
    }
}

// ---------------- fp32 vector GEMM (kept for dt: K=64) ----------------
template <typename TA, typename TW, typename TC, int ACT, bool FLIP>
__global__ __launch_bounds__(256) void gemm_kernel(
    const TA* __restrict__ A, int lda,
    const TW* __restrict__ W,
    const TW* __restrict__ bias,
    TC* __restrict__ C, int ldc,
    int M, int N, int K)
{
    __shared__ float As[16][65];
    __shared__ float Ws[16][65];
    const int tid = threadIdx.x;
    const int tx = tid & 15;
    const int ty = tid >> 4;
    const int m0 = blockIdx.y * 64;
    const int n0 = blockIdx.x * 64;

    float acc[4][4] = {};
    const int lm = tid >> 2;
    const int lk = (tid & 3) * 4;

    for (int k0 = 0; k0 < K; k0 += 16) {
        {
            int gm = m0 + lm;
            #pragma unroll
            for (int i = 0; i < 4; i++) {
                int gk = k0 + lk + i;
                float v = 0.f;
                if (gm < M) v = ldf(A, (size_t)gm * lda + gk);
                As[lk + i][lm] = v;
            }
            int gn = n0 + lm;
            #pragma unroll
            for (int i = 0; i < 4; i++) {
                int gk = k0 + lk + i;
                float v = 0.f;
                if (gn < N) v = ldf(W, (size_t)gn * K + gk);
                Ws[lk + i][lm] = v;
            }
        }
        __syncthreads();
        #pragma unroll
        for (int k = 0; k < 16; k++) {
            float a[4], w[4];
            #pragma unroll
            for (int i = 0; i < 4; i++) a[i] = As[k][ty * 4 + i];
            #pragma unroll
            for (int j = 0; j < 4; j++) w[j] = Ws[k][tx * 4 + j];
            #pragma unroll
            for (int i = 0; i < 4; i++)
                #pragma unroll
                for (int j = 0; j < 4; j++) acc[i][j] += a[i] * w[j];
        }
        __syncthreads();
    }

    #pragma unroll
    for (int i = 0; i < 4; i++) {
        int gm = m0 + ty * 4 + i;
        if (gm >= M) continue;
        int om = gm;
        if (FLIP) {
            int b = gm / SEQ, l = gm % SEQ;
            om = b * SEQ + (SEQ - 1 - l);
        }
        #pragma unroll
        for (int j = 0; j < 4; j++) {
            int gn = n0 + tx * 4 + j;
            if (gn >= N) continue;
            float v = acc[i][j];
            if (ACT == 1) v = softplus_fast(v + ldf(bias, gn));
            stf(C, (size_t)om * ldc + gn, v);
        }
    }
}

// conv + silu; writes fp32 xc (for scan) and bf16 xcb (for x_proj MFMA)
__global__ __launch_bounds__(256) void conv_silu_kernel(
    const float* __restrict__ xz, const float* __restrict__ conv_w,
    const float* __restrict__ conv_b, float* __restrict__ xc,
    u16* __restrict__ xcb)
{
    int idx = blockIdx.x * 256 + threadIdx.x;
    if (idx >= BSZ * SEQ * DI) return;
    int e = idx & (DI - 1);
    int bl = idx / DI;
    int l = bl & (SEQ - 1);
    float acc = conv_b[e];
    #pragma unroll
    for (int k = 0; k < DC; k++) {
        int ll = l + k - (DC - 1);
        if (ll >= 0)
            acc += conv_w[e * DC + k] * xz[((size_t)(bl - l + ll)) * (2 * DI) + e];
    }
    acc = silu_fast(acc);
    xc[idx] = acc;
    xcb[idx] = f2b(acc);
}

// ---- Chunked scan ----
__global__ __launch_bounds__(256) void scan_pass1(
    const float* __restrict__ dbl,
    const float* __restrict__ xc,
    const u16*  __restrict__ delta,
    const float* __restrict__ A_log,
    float* __restrict__ Pout, float* __restrict__ Qout)
{
    const int tid = threadIdx.x;
    const int n = tid & 15;
    const int eg = tid >> 4;
    const int c = blockIdx.x;
    const int e = blockIdx.y * 16 + eg;
    const int b = blockIdx.z;

    const float Aen = -fexp(A_log[e * DS + n]);
    float P = 1.f, q = 0.f;
    const int row0 = b * SEQ + c * LC;
    #pragma unroll 4
    for (int i = 0; i < LC; i++) {
        size_t row = (size_t)(row0 + i);
        float dv = b2f(delta[row * DI + e]);
        float xv = xc[row * DI + e];
        float Bv = dbl[row * NDBL + DR + n];
        float dA = fexp(dv * Aen);
        P *= dA;
        q = dA * q + (dv * xv) * Bv;
    }
    size_t idx = ((size_t)(b * NC + c) * DI + e) * DS + n;
    Pout[idx] = P;
    Qout[idx] = q;
}

__global__ __launch_bounds__(256) void scan_pass2(
    const float* __restrict__ P, const float* __restrict__ Q,
    float* __restrict__ H0)
{
    const int gid = blockIdx.x * 256 + threadIdx.x;
    const int en = gid & (DI * DS - 1);
    const int b = gid >> 15;
    float h = 0.f;
    for (int c = 0; c < NC; c++) {
        size_t idx = ((size_t)(b * NC + c) * DI * DS) + en;
        H0[idx] = h;
        h = P[idx] * h + Q[idx];
    }
}

__global__ __launch_bounds__(256) void scan_pass3(
    const float* __restrict__ dbl,
    const float* __restrict__ xc,
    const float* __restrict__ xz,      // z = cols [DI, 2*DI)
    const u16*  __restrict__ delta,
    const float* __restrict__ A_log,
    const float* __restrict__ Dp,
    const float* __restrict__ H0,
    u16* __restrict__ ybf)             // output (bf16, feeds out_proj MFMA)
{
    const int tid = threadIdx.x;
    const int n = tid & 15;
    const int eg = tid >> 4;
    const int c = blockIdx.x;
    const int e = blockIdx.y * 16 + eg;
    const int b = blockIdx.z;

    const float Aen = -fexp(A_log[e * DS + n]);
    const float Dv  = Dp[e];
    float h = H0[((size_t)(b * NC + c) * DI + e) * DS + n];
    const int row0 = b * SEQ + c * LC;
    #pragma unroll 4
    for (int i = 0; i < LC; i++) {
        size_t row = (size_t)(row0 + i);
        float dv = b2f(delta[row * DI + e]);
        float xv = xc[row * DI + e];
        float Bv = dbl[row * NDBL + DR + n];
        float Cv = dbl[row * NDBL + DR + DS + n];
        h = fexp(dv * Aen) * h + (dv * xv) * Bv;
        float p = h * Cv;
        p += __shfl_xor(p, 1, 64);
        p += __shfl_xor(p, 2, 64);
        p += __shfl_xor(p, 4, 64);
        p += __shfl_xor(p, 8, 64);
        if (n == 0) {
            float zv = xz[row * (2 * DI) + DI + e];
            float y = (p + xv * Dv) * silu_fast(zv);
            ybf[row * DI + e] = f2b(y);
        }
    }
}

static inline void cvt(const float* in, u16* out, int n, hipStream_t s) {
    int n4 = n / 4;
    cvt_f2b_kernel<<<(n4 + 255) / 256, 256, 0, s>>>(in, out, n4);
}

extern "C" void kernel_launch(void* const* d_in, const int* in_sizes, int n_in,
                              void* d_out, int out_size, void* d_ws, size_t ws_size,
                              hipStream_t stream)
{
    const float* x = (const float*)d_in[0];
    const float* merge_w = (const float*)d_in[19];
    float* out = (float*)d_out;

    const int M = BSZ * SEQ;   // 2048

    // workspace layout (float units); xcb aliases Q, ybf aliases P
    float* ws = (float*)d_ws;
    float* ws_xz  = ws;                                   // 8,388,608 f
    float* ws_xc  = ws_xz  + (size_t)M * 2 * DI;          // 4,194,304 f
    float* ws_dbl = ws_xc  + (size_t)M * DI;              //   196,608 f
    float* ws_P   = ws_dbl + (size_t)M * NDBL;            // 2,097,152 f
    float* ws_Q   = ws_P   + (size_t)BSZ * NC * DI * DS;  // 2,097,152 f
    float* ws_H0  = ws_Q   + (size_t)BSZ * NC * DI * DS;  // 2,097,152 f
    u16* ws_delta = (u16*)(ws_H0 + (size_t)BSZ * NC * DI * DS);  // M*DI u16
    u16* ws_cat   = ws_delta + (size_t)M * DI;            // M*2DM u16
    u16* ws_xbf   = ws_cat   + (size_t)M * 2 * DM;        // M*DM u16
    u16* ws_wbf   = ws_xbf   + (size_t)M * DM;            // 4,194,304 u16 (shared weights)
    u16* ws_xcb   = (u16*)ws_Q;                           // alias: dead before pass1 writes Q
    u16* ws_ybf   = (u16*)ws_P;                           // alias: dead before pass3 writes ybf

    cvt(x, ws_xbf, M * DM, stream);

    for (int dir = 0; dir < 2; dir++) {
        const float* in_proj  = (const float*)d_in[1 + 9 * dir + 0];
        const float* conv_w   = (const float*)d_in[1 + 9 * dir + 1];
        const float* conv_b   = (const float*)d_in[1 + 9 * dir + 2];
        const float* x_proj   = (const float*)d_in[1 + 9 * dir + 3];
        const float* dt_w     = (const float*)d_in[1 + 9 * dir + 4];
        const float* dt_b     = (const float*)d_in[1 + 9 * dir + 5];
        const float* A_log    = (const float*)d_in[1 + 9 * dir + 6];
        const float* Dp       = (const float*)d_in[1 + 9 * dir + 7];
        const float* out_proj = (const float*)d_in[1 + 9 * dir + 8];

        // 1) xz = x @ in_proj^T (bwd: flip output rows)
        cvt(in_proj, ws_wbf, 2 * DI * DM, stream);
        {
            dim3 grid((2 * DI) / 128, M / 128);
            if (dir == 0)
                mfma_gemm<float, false><<<grid, 256, 0, stream>>>(
                    ws_xbf, ws_wbf, ws_xz, 2 * DI, M, 2 * DI, DM);
            else
                mfma_gemm<float, true><<<grid, 256, 0, stream>>>(
                    ws_xbf, ws_wbf, ws_xz, 2 * DI, M, 2 * DI, DM);
        }

        // 2) conv + silu
        conv_silu_kernel<<<(M * DI) / 256, 256, 0, stream>>>(
            ws_xz, conv_w, conv_b, ws_xc, ws_xcb);

        // 3) dbl = xc @ x_proj^T  (N=96, guarded)
        cvt(x_proj, ws_wbf, NDBL * DI, stream);
        {
            dim3 grid(1, M / 128);
            mfma_gemm<float, false><<<grid, 256, 0, stream>>>(
                ws_xcb, ws_wbf, ws_dbl, NDBL, M, NDBL, DI);
        }

        // 4) delta = softplus(dt @ dt_w^T + dt_b)  -> bf16 (vector GEMM, K=64)
        {
            dim3 grid(DI / 64, M / 64);
            gemm_kernel<float, float, u16, 1, false><<<grid, 256, 0, stream>>>(
                ws_dbl, NDBL, dt_w, dt_b, ws_delta, DI, M, DI, DR);
        }

        // 5) chunked scan
        {
            dim3 grid(NC, DI / 16, BSZ);
            scan_pass1<<<grid, 256, 0, stream>>>(ws_dbl, ws_xc, ws_delta, A_log, ws_P, ws_Q);
            scan_pass2<<<(BSZ * DI * DS) / 256, 256, 0, stream>>>(ws_P, ws_Q, ws_H0);
            scan_pass3<<<grid, 256, 0, stream>>>(ws_dbl, ws_xc, ws_xz, ws_delta,
                                                 A_log, Dp, ws_H0, ws_ybf);
        }

        // 6) cat[:, dir*DM:+DM] = y @ out_proj^T (bwd: flip rows back)
        cvt(out_proj, ws_wbf, DM * DI, stream);
        {
            dim3 grid(DM / 128, M / 128);
            if (dir == 0)
                mfma_gemm<u16, false><<<grid, 256, 0, stream>>>(
                    ws_ybf, ws_wbf, ws_cat, 2 * DM, M, DM, DI);
            else
                mfma_gemm<u16, true><<<grid, 256, 0, stream>>>(
                    ws_ybf, ws_wbf, ws_cat + DM, 2 * DM, M, DM, DI);
        }
    }

    // 7) out = cat @ merge_w^T (fp32 out)
    cvt(merge_w, ws_wbf, DM * 2 * DM, stream);
    {
        dim3 grid(DM / 128, M / 128);
        mfma_gemm<float, false><<<grid, 256, 0, stream>>>(
            ws_cat, ws_wbf, out, DM, M, DM, 2 * DM);
    }
}

// Round 6
// 720.529 us; speedup vs baseline: 4.9935x; 1.2917x over previous
//
#include <hip/hip_runtime.h>
#include <math.h>

#define BSZ 2
#define SEQ 1024
#define DM  1024          // d_model
#define DI  2048          // d_inner
#define DS  16            // d_state
#define DC  4             // d_conv
#define DR  64            // dt_rank
#define NDBL 96           // DR + 2*DS
#define NC  32            // scan chunks
#define LC  32            // SEQ / NC

typedef unsigned short u16;
typedef __bf16 bf16x8 __attribute__((ext_vector_type(8)));
typedef float  f32x4  __attribute__((ext_vector_type(4)));

__device__ __forceinline__ u16 f2b(float f) {
    unsigned int u = __float_as_uint(f);
    unsigned int r = (u + 0x7fffu + ((u >> 16) & 1u)) >> 16;
    return (u16)r;
}
__device__ __forceinline__ float b2f(u16 h) {
    return __uint_as_float(((unsigned int)h) << 16);
}

__device__ __forceinline__ float ldf(const float* p, size_t i) { return p[i]; }
__device__ __forceinline__ float ldf(const u16* p, size_t i)   { return b2f(p[i]); }
__device__ __forceinline__ void  stf(float* p, size_t i, float v) { p[i] = v; }
__device__ __forceinline__ void  stf(u16* p, size_t i, float v)   { p[i] = f2b(v); }

// ---- fast transcendentals ----
__device__ __forceinline__ float fexp(float x)  { return __expf(x); }
__device__ __forceinline__ float frcp(float x)  { return __builtin_amdgcn_rcpf(x); }
__device__ __forceinline__ float silu_fast(float x) {
    return x * frcp(1.f + fexp(-x));
}
__device__ __forceinline__ float softplus_fast(float x) {
    return (x > 15.f) ? x : __logf(1.f + fexp(x));
}

// fp32 -> bf16 pack, 4 elems/thread.
__global__ __launch_bounds__(256) void cvt_f2b_kernel(
    const float* __restrict__ in, u16* __restrict__ out, int n4)
{
    int i = blockIdx.x * 256 + threadIdx.x;
    if (i >= n4) return;
    float4 v = ((const float4*)in)[i];
    ushort4 o;
    o.x = f2b(v.x); o.y = f2b(v.y); o.z = f2b(v.z); o.w = f2b(v.w);
    ((ushort4*)out)[i] = o;
}

// ---------------- MFMA GEMM: C[M,N] = A[M,K] @ W[N,K]^T ----------------
template <typename TC, bool FLIP>
__global__ __launch_bounds__(256) void mfma_gemm(
    const u16* __restrict__ A,
    const u16* __restrict__ W,
    TC* __restrict__ C, int ldc,
    int M, int N, int K)
{
    __shared__ u16 As[128 * 32];
    __shared__ u16 Ws[128 * 32];

    const int t = threadIdx.x;
    const int wave = t >> 6;
    const int lane = t & 63;
    const int wm = (wave & 1) * 64;
    const int wn = (wave >> 1) * 64;
    const int fm = lane & 15;
    const int fk = (lane >> 4) * 8;
    const int m0 = blockIdx.y * 128;
    const int n0 = blockIdx.x * 128;

    f32x4 acc[4][4] = {};

    for (int k0 = 0; k0 < K; k0 += 32) {
        #pragma unroll
        for (int p = 0; p < 2; p++) {
            int elem = p * 256 + t;
            int r = elem >> 2;
            int c = (elem & 3) * 8;
            *(uint4*)&As[r * 32 + c] =
                *(const uint4*)(A + (size_t)(m0 + r) * K + k0 + c);
            uint4 wv = {0u, 0u, 0u, 0u};
            int gn = n0 + r;
            if (gn < N) wv = *(const uint4*)(W + (size_t)gn * K + k0 + c);
            *(uint4*)&Ws[r * 32 + c] = wv;
        }
        __syncthreads();

        bf16x8 af[4], wf[4];
        #pragma unroll
        for (int mi = 0; mi < 4; mi++)
            af[mi] = *(const bf16x8*)&As[(wm + mi * 16 + fm) * 32 + fk];
        #pragma unroll
        for (int ni = 0; ni < 4; ni++)
            wf[ni] = *(const bf16x8*)&Ws[(wn + ni * 16 + fm) * 32 + fk];
        #pragma unroll
        for (int mi = 0; mi < 4; mi++)
            #pragma unroll
            for (int ni = 0; ni < 4; ni++)
                acc[mi][ni] = __builtin_amdgcn_mfma_f32_16x16x32_bf16(
                    af[mi], wf[ni], acc[mi][ni], 0, 0, 0);
        __syncthreads();
    }

    const int rb = (lane >> 4) * 4;
    const int cc = lane & 15;
    #pragma unroll
    for (int mi = 0; mi < 4; mi++) {
        #pragma unroll
        for (int r = 0; r < 4; r++) {
            int gm = m0 + wm + mi * 16 + rb + r;
            int om = gm;
            if (FLIP) {
                int b = gm / SEQ, l = gm % SEQ;
                om = b * SEQ + (SEQ - 1 - l);
            }
            #pragma unroll
            for (int ni = 0; ni < 4; ni++) {
                int gn = n0 + wn + ni * 16 + cc;
                if (gn < N) stf(C, (size_t)om * ldc + gn, acc[mi][ni][r]);
            }
        }
    }
}

// ---------------- fp32 vector GEMM (kept for dt: K=64) ----------------
template <typename TA, typename TW, typename TC, int ACT, bool FLIP>
__global__ __launch_bounds__(256) void gemm_kernel(
    const TA* __restrict__ A, int lda,
    const TW* __restrict__ W,
    const TW* __restrict__ bias,
    TC* __restrict__ C, int ldc,
    int M, int N, int K)
{
    __shared__ float As[16][65];
    __shared__ float Ws[16][65];
    const int tid = threadIdx.x;
    const int tx = tid & 15;
    const int ty = tid >> 4;
    const int m0 = blockIdx.y * 64;
    const int n0 = blockIdx.x * 64;

    float acc[4][4] = {};
    const int lm = tid >> 2;
    const int lk = (tid & 3) * 4;

    for (int k0 = 0; k0 < K; k0 += 16) {
        {
            int gm = m0 + lm;
            #pragma unroll
            for (int i = 0; i < 4; i++) {
                int gk = k0 + lk + i;
                float v = 0.f;
                if (gm < M) v = ldf(A, (size_t)gm * lda + gk);
                As[lk + i][lm] = v;
            }
            int gn = n0 + lm;
            #pragma unroll
            for (int i = 0; i < 4; i++) {
                int gk = k0 + lk + i;
                float v = 0.f;
                if (gn < N) v = ldf(W, (size_t)gn * K + gk);
                Ws[lk + i][lm] = v;
            }
        }
        __syncthreads();
        #pragma unroll
        for (int k = 0; k < 16; k++) {
            float a[4], w[4];
            #pragma unroll
            for (int i = 0; i < 4; i++) a[i] = As[k][ty * 4 + i];
            #pragma unroll
            for (int j = 0; j < 4; j++) w[j] = Ws[k][tx * 4 + j];
            #pragma unroll
            for (int i = 0; i < 4; i++)
                #pragma unroll
                for (int j = 0; j < 4; j++) acc[i][j] += a[i] * w[j];
        }
        __syncthreads();
    }

    #pragma unroll
    for (int i = 0; i < 4; i++) {
        int gm = m0 + ty * 4 + i;
        if (gm >= M) continue;
        int om = gm;
        if (FLIP) {
            int b = gm / SEQ, l = gm % SEQ;
            om = b * SEQ + (SEQ - 1 - l);
        }
        #pragma unroll
        for (int j = 0; j < 4; j++) {
            int gn = n0 + tx * 4 + j;
            if (gn >= N) continue;
            float v = acc[i][j];
            if (ACT == 1) v = softplus_fast(v + ldf(bias, gn));
            stf(C, (size_t)om * ldc + gn, v);
        }
    }
}

// conv + silu; writes fp32 xc (for scan) and bf16 xcb (for x_proj MFMA)
__global__ __launch_bounds__(256) void conv_silu_kernel(
    const float* __restrict__ xz, const float* __restrict__ conv_w,
    const float* __restrict__ conv_b, float* __restrict__ xc,
    u16* __restrict__ xcb)
{
    int idx = blockIdx.x * 256 + threadIdx.x;
    if (idx >= BSZ * SEQ * DI) return;
    int e = idx & (DI - 1);
    int bl = idx / DI;
    int l = bl & (SEQ - 1);
    float acc = conv_b[e];
    #pragma unroll
    for (int k = 0; k < DC; k++) {
        int ll = l + k - (DC - 1);
        if (ll >= 0)
            acc += conv_w[e * DC + k] * xz[((size_t)(bl - l + ll)) * (2 * DI) + e];
    }
    acc = silu_fast(acc);
    xc[idx] = acc;
    xcb[idx] = f2b(acc);
}

// ---- Chunked scan, n-in-registers. Thread = one e; 16 n-states in VGPRs. ----
// grid (NC, DI/256, BSZ), block 256.

__global__ __launch_bounds__(256) void scan_pass1(
    const float* __restrict__ dbl,
    const float* __restrict__ xc,
    const u16*  __restrict__ delta,
    const float* __restrict__ A_log,
    float* __restrict__ Pout, float* __restrict__ Qout)
{
    __shared__ float sB[LC][16];
    const int t = threadIdx.x;
    const int c = blockIdx.x;
    const int b = blockIdx.z;
    const int e = blockIdx.y * 256 + t;
    const int row0 = b * SEQ + c * LC;

    if (t < LC * 4) {   // stage B rows: LC x 16 floats
        int row = t >> 2, col = (t & 3) * 4;
        *(f32x4*)&sB[row][col] =
            *(const f32x4*)&dbl[(size_t)(row0 + row) * NDBL + DR + col];
    }

    f32x4 Aen[4], P[4], Q[4];
    #pragma unroll
    for (int g = 0; g < 4; g++) {
        f32x4 a = *(const f32x4*)&A_log[(size_t)e * DS + g * 4];
        #pragma unroll
        for (int j = 0; j < 4; j++) Aen[g][j] = -fexp(a[j]);
        P[g] = f32x4{1.f, 1.f, 1.f, 1.f};
        Q[g] = f32x4{0.f, 0.f, 0.f, 0.f};
    }
    __syncthreads();

    float dv = b2f(delta[(size_t)row0 * DI + e]);
    float xv = xc[(size_t)row0 * DI + e];
    for (int i = 0; i < LC; i++) {
        int ip = (i + 1 < LC) ? (i + 1) : (LC - 1);
        float dvn = b2f(delta[(size_t)(row0 + ip) * DI + e]);
        float xvn = xc[(size_t)(row0 + ip) * DI + e];
        float du = dv * xv;
        #pragma unroll
        for (int g = 0; g < 4; g++) {
            f32x4 Bv = *(const f32x4*)&sB[i][g * 4];
            #pragma unroll
            for (int j = 0; j < 4; j++) {
                float dA = fexp(dv * Aen[g][j]);
                P[g][j] *= dA;
                Q[g][j] = dA * Q[g][j] + du * Bv[j];
            }
        }
        dv = dvn; xv = xvn;
    }
    size_t base = ((size_t)(b * NC + c) * DI + e) * DS;
    #pragma unroll
    for (int g = 0; g < 4; g++) {
        *(f32x4*)&Pout[base + g * 4] = P[g];
        *(f32x4*)&Qout[base + g * 4] = Q[g];
    }
}

__global__ __launch_bounds__(256) void scan_pass2(
    const float* __restrict__ P, const float* __restrict__ Q,
    float* __restrict__ H0)
{
    const int gid = blockIdx.x * 256 + threadIdx.x;
    const int en = gid & (DI * DS - 1);
    const int b = gid >> 15;
    float h = 0.f;
    for (int c = 0; c < NC; c++) {
        size_t idx = ((size_t)(b * NC + c) * DI * DS) + en;
        H0[idx] = h;
        h = P[idx] * h + Q[idx];
    }
}

__global__ __launch_bounds__(256) void scan_pass3(
    const float* __restrict__ dbl,
    const float* __restrict__ xc,
    const float* __restrict__ xz,      // z = cols [DI, 2*DI)
    const u16*  __restrict__ delta,
    const float* __restrict__ A_log,
    const float* __restrict__ Dp,
    const float* __restrict__ H0,
    u16* __restrict__ ybf)             // output (bf16, feeds out_proj MFMA)
{
    __shared__ float sBC[LC][32];      // cols 0..15 = B, 16..31 = C
    const int t = threadIdx.x;
    const int c = blockIdx.x;
    const int b = blockIdx.z;
    const int e = blockIdx.y * 256 + t;
    const int row0 = b * SEQ + c * LC;

    {   // stage B+C rows: LC x 32 floats = 256 float4s, one per thread
        int row = t >> 3, col = (t & 7) * 4;
        *(f32x4*)&sBC[row][col] =
            *(const f32x4*)&dbl[(size_t)(row0 + row) * NDBL + DR + col];
    }

    f32x4 Aen[4], h[4];
    size_t base = ((size_t)(b * NC + c) * DI + e) * DS;
    #pragma unroll
    for (int g = 0; g < 4; g++) {
        f32x4 a = *(const f32x4*)&A_log[(size_t)e * DS + g * 4];
        #pragma unroll
        for (int j = 0; j < 4; j++) Aen[g][j] = -fexp(a[j]);
        h[g] = *(const f32x4*)&H0[base + g * 4];
    }
    const float Dv = Dp[e];
    __syncthreads();

    float dv = b2f(delta[(size_t)row0 * DI + e]);
    float xv = xc[(size_t)row0 * DI + e];
    float zv = xz[(size_t)row0 * (2 * DI) + DI + e];
    for (int i = 0; i < LC; i++) {
        int ip = (i + 1 < LC) ? (i + 1) : (LC - 1);
        float dvn = b2f(delta[(size_t)(row0 + ip) * DI + e]);
        float xvn = xc[(size_t)(row0 + ip) * DI + e];
        float zvn = xz[(size_t)(row0 + ip) * (2 * DI) + DI + e];
        float du = dv * xv;
        f32x4 pv = {0.f, 0.f, 0.f, 0.f};
        #pragma unroll
        for (int g = 0; g < 4; g++) {
            f32x4 Bv = *(const f32x4*)&sBC[i][g * 4];
            f32x4 Cv = *(const f32x4*)&sBC[i][16 + g * 4];
            #pragma unroll
            for (int j = 0; j < 4; j++) {
                float dA = fexp(dv * Aen[g][j]);
                h[g][j] = dA * h[g][j] + du * Bv[j];
                pv[j] += h[g][j] * Cv[j];
            }
        }
        float p = pv[0] + pv[1] + pv[2] + pv[3];
        float y = (p + xv * Dv) * silu_fast(zv);
        ybf[(size_t)(row0 + i) * DI + e] = f2b(y);
        dv = dvn; xv = xvn; zv = zvn;
    }
}

static inline void cvt(const float* in, u16* out, int n, hipStream_t s) {
    int n4 = n / 4;
    cvt_f2b_kernel<<<(n4 + 255) / 256, 256, 0, s>>>(in, out, n4);
}

extern "C" void kernel_launch(void* const* d_in, const int* in_sizes, int n_in,
                              void* d_out, int out_size, void* d_ws, size_t ws_size,
                              hipStream_t stream)
{
    const float* x = (const float*)d_in[0];
    const float* merge_w = (const float*)d_in[19];
    float* out = (float*)d_out;

    const int M = BSZ * SEQ;   // 2048

    // workspace layout (float units); xcb aliases Q, ybf aliases P
    float* ws = (float*)d_ws;
    float* ws_xz  = ws;                                   // 8,388,608 f
    float* ws_xc  = ws_xz  + (size_t)M * 2 * DI;          // 4,194,304 f
    float* ws_dbl = ws_xc  + (size_t)M * DI;              //   196,608 f
    float* ws_P   = ws_dbl + (size_t)M * NDBL;            // 2,097,152 f
    float* ws_Q   = ws_P   + (size_t)BSZ * NC * DI * DS;  // 2,097,152 f
    float* ws_H0  = ws_Q   + (size_t)BSZ * NC * DI * DS;  // 2,097,152 f
    u16* ws_delta = (u16*)(ws_H0 + (size_t)BSZ * NC * DI * DS);  // M*DI u16
    u16* ws_cat   = ws_delta + (size_t)M * DI;            // M*2DM u16
    u16* ws_xbf   = ws_cat   + (size_t)M * 2 * DM;        // M*DM u16
    u16* ws_wbf   = ws_xbf   + (size_t)M * DM;            // 4,194,304 u16 (shared weights)
    u16* ws_xcb   = (u16*)ws_Q;                           // alias: dead before pass1 writes Q
    u16* ws_ybf   = (u16*)ws_P;                           // alias: dead before pass3 writes ybf

    cvt(x, ws_xbf, M * DM, stream);

    for (int dir = 0; dir < 2; dir++) {
        const float* in_proj  = (const float*)d_in[1 + 9 * dir + 0];
        const float* conv_w   = (const float*)d_in[1 + 9 * dir + 1];
        const float* conv_b   = (const float*)d_in[1 + 9 * dir + 2];
        const float* x_proj   = (const float*)d_in[1 + 9 * dir + 3];
        const float* dt_w     = (const float*)d_in[1 + 9 * dir + 4];
        const float* dt_b     = (const float*)d_in[1 + 9 * dir + 5];
        const float* A_log    = (const float*)d_in[1 + 9 * dir + 6];
        const float* Dp       = (const float*)d_in[1 + 9 * dir + 7];
        const float* out_proj = (const float*)d_in[1 + 9 * dir + 8];

        // 1) xz = x @ in_proj^T (bwd: flip output rows)
        cvt(in_proj, ws_wbf, 2 * DI * DM, stream);
        {
            dim3 grid((2 * DI) / 128, M / 128);
            if (dir == 0)
                mfma_gemm<float, false><<<grid, 256, 0, stream>>>(
                    ws_xbf, ws_wbf, ws_xz, 2 * DI, M, 2 * DI, DM);
            else
                mfma_gemm<float, true><<<grid, 256, 0, stream>>>(
                    ws_xbf, ws_wbf, ws_xz, 2 * DI, M, 2 * DI, DM);
        }

        // 2) conv + silu
        conv_silu_kernel<<<(M * DI) / 256, 256, 0, stream>>>(
            ws_xz, conv_w, conv_b, ws_xc, ws_xcb);

        // 3) dbl = xc @ x_proj^T  (N=96, guarded)
        cvt(x_proj, ws_wbf, NDBL * DI, stream);
        {
            dim3 grid(1, M / 128);
            mfma_gemm<float, false><<<grid, 256, 0, stream>>>(
                ws_xcb, ws_wbf, ws_dbl, NDBL, M, NDBL, DI);
        }

        // 4) delta = softplus(dt @ dt_w^T + dt_b)  -> bf16 (vector GEMM, K=64)
        {
            dim3 grid(DI / 64, M / 64);
            gemm_kernel<float, float, u16, 1, false><<<grid, 256, 0, stream>>>(
                ws_dbl, NDBL, dt_w, dt_b, ws_delta, DI, M, DI, DR);
        }

        // 5) chunked scan (n-in-registers)
        {
            dim3 grid(NC, DI / 256, BSZ);
            scan_pass1<<<grid, 256, 0, stream>>>(ws_dbl, ws_xc, ws_delta, A_log, ws_P, ws_Q);
            scan_pass2<<<(BSZ * DI * DS) / 256, 256, 0, stream>>>(ws_P, ws_Q, ws_H0);
            scan_pass3<<<grid, 256, 0, stream>>>(ws_dbl, ws_xc, ws_xz, ws_delta,
                                                 A_log, Dp, ws_H0, ws_ybf);
        }

        // 6) cat[:, dir*DM:+DM] = y @ out_proj^T (bwd: flip rows back)
        cvt(out_proj, ws_wbf, DM * DI, stream);
        {
            dim3 grid(DM / 128, M / 128);
            if (dir == 0)
                mfma_gemm<u16, false><<<grid, 256, 0, stream>>>(
                    ws_ybf, ws_wbf, ws_cat, 2 * DM, M, DM, DI);
            else
                mfma_gemm<u16, true><<<grid, 256, 0, stream>>>(
                    ws_ybf, ws_wbf, ws_cat + DM, 2 * DM, M, DM, DI);
        }
    }

    // 7) out = cat @ merge_w^T (fp32 out)
    cvt(merge_w, ws_wbf, DM * 2 * DM, stream);
    {
        dim3 grid(DM / 128, M / 128);
        mfma_gemm<float, false><<<grid, 256, 0, stream>>>(
            ws_cat, ws_wbf, out, DM, M, DM, 2 * DM);
    }
}

// Round 7
// 603.758 us; speedup vs baseline: 5.9593x; 1.1934x over previous
//
#include <hip/hip_runtime.h>
#include <math.h>

#define BSZ 2
#define SEQ 1024
#define DM  1024          // d_model
#define DI  2048          // d_inner
#define DS  16            // d_state
#define DC  4             // d_conv
#define DR  64            // dt_rank
#define NDBL 96           // DR + 2*DS
#define NC  32            // scan chunks
#define LC  32            // SEQ / NC

typedef unsigned short u16;
typedef __bf16 bf16x8 __attribute__((ext_vector_type(8)));
typedef float  f32x4  __attribute__((ext_vector_type(4)));

__device__ __forceinline__ u16 f2b(float f) {
    unsigned int u = __float_as_uint(f);
    unsigned int r = (u + 0x7fffu + ((u >> 16) & 1u)) >> 16;
    return (u16)r;
}
__device__ __forceinline__ float b2f(u16 h) {
    return __uint_as_float(((unsigned int)h) << 16);
}

__device__ __forceinline__ void stf(float* p, size_t i, float v) { p[i] = v; }
__device__ __forceinline__ void stf(u16* p, size_t i, float v)   { p[i] = f2b(v); }

// ---- fast transcendentals ----
__device__ __forceinline__ float fexp(float x)  { return __expf(x); }
__device__ __forceinline__ float frcp(float x)  { return __builtin_amdgcn_rcpf(x); }
__device__ __forceinline__ float silu_fast(float x) {
    return x * frcp(1.f + fexp(-x));
}
__device__ __forceinline__ float softplus_fast(float x) {
    return (x > 15.f) ? x : __logf(1.f + fexp(x));
}

// ---- staging helpers: 8 contiguous elements -> LDS as bf16 ----
__device__ __forceinline__ void stage8(const u16* p, u16* d) {
    *(uint4*)d = *(const uint4*)p;
}
__device__ __forceinline__ void stage8(const float* p, u16* d) {
    float4 v0 = *(const float4*)p;
    float4 v1 = *(const float4*)(p + 4);
    ushort4 a; a.x = f2b(v0.x); a.y = f2b(v0.y); a.z = f2b(v0.z); a.w = f2b(v0.w);
    ushort4 b; b.x = f2b(v1.x); b.y = f2b(v1.y); b.z = f2b(v1.z); b.w = f2b(v1.w);
    *(ushort4*)d = a;
    *(ushort4*)(d + 4) = b;
}

// fp32 -> bf16 pack, 4 elems/thread.
__global__ __launch_bounds__(256) void cvt_f2b_kernel(
    const float* __restrict__ in, u16* __restrict__ out, int n4)
{
    int i = blockIdx.x * 256 + threadIdx.x;
    if (i >= n4) return;
    float4 v = ((const float4*)in)[i];
    ushort4 o; o.x = f2b(v.x); o.y = f2b(v.y); o.z = f2b(v.z); o.w = f2b(v.w);
    ((ushort4*)out)[i] = o;
}

// 4-segment fused weight convert (sizes in float4 units)
__global__ __launch_bounds__(256) void cvt4_kernel(
    const float* __restrict__ s0, int n0, const float* __restrict__ s1, int n1,
    const float* __restrict__ s2, int n2, const float* __restrict__ s3, int n3,
    u16* __restrict__ d0, u16* __restrict__ d1,
    u16* __restrict__ d2, u16* __restrict__ d3)
{
    int i = blockIdx.x * 256 + threadIdx.x;
    const float* s; u16* d;
    if (i < n0) { s = s0; d = d0; }
    else if ((i -= n0) < n1) { s = s1; d = d1; }
    else if ((i -= n1) < n2) { s = s2; d = d2; }
    else if ((i -= n2) < n3) { s = s3; d = d3; }
    else return;
    float4 v = ((const float4*)s)[i];
    ushort4 o; o.x = f2b(v.x); o.y = f2b(v.y); o.z = f2b(v.z); o.w = f2b(v.w);
    ((ushort4*)d)[i] = o;
}

// ---------------- MFMA GEMM: C[M,N] = act(A[M,K] @ W[N,K]^T + bias) --------
// Tile 128(M) x 64(N), BK=32, 256 threads = 4 waves in 2x2, wave tile 64x32.
// A: bf16(u16) or fp32 (converted in staging). W: bf16(u16), row stride ldw.
// LDS row stride 40 u16 (20 banks -> 2-way aliasing = free).
template <typename TA, typename TC, int ACT, bool FLIP>
__global__ __launch_bounds__(256) void mfma_gemm(
    const TA* __restrict__ A, int lda,
    const u16* __restrict__ W, int ldw,
    const float* __restrict__ bias,
    TC* __restrict__ C, int ldc,
    int M, int N, int K)
{
    constexpr int RS = 40;
    __shared__ u16 As[128 * RS];
    __shared__ u16 Ws[64 * RS];

    const int t = threadIdx.x;
    const int wave = t >> 6;
    const int lane = t & 63;
    const int wm = (wave & 1) * 64;
    const int wn = (wave >> 1) * 32;
    const int fm = lane & 15;
    const int fk = (lane >> 4) * 8;
    const int m0 = blockIdx.y * 128;
    const int n0 = blockIdx.x * 64;

    f32x4 acc[4][2] = {};

    for (int k0 = 0; k0 < K; k0 += 32) {
        #pragma unroll
        for (int p = 0; p < 2; p++) {       // A tile: 128x32
            int elem = p * 256 + t;
            int r = elem >> 2, c = (elem & 3) * 8;
            stage8(A + (size_t)(m0 + r) * lda + k0 + c, &As[r * RS + c]);
        }
        {                                   // W tile: 64x32
            int r = t >> 2, c = (t & 3) * 8;
            int gn = n0 + r;
            if (gn < N) {
                stage8(W + (size_t)gn * ldw + k0 + c, &Ws[r * RS + c]);
            } else {
                ushort4 z4; z4.x = z4.y = z4.z = z4.w = 0;
                *(ushort4*)&Ws[r * RS + c] = z4;
                *(ushort4*)&Ws[r * RS + c + 4] = z4;
            }
        }
        __syncthreads();

        bf16x8 af[4], wf[2];
        #pragma unroll
        for (int mi = 0; mi < 4; mi++)
            af[mi] = *(const bf16x8*)&As[(wm + mi * 16 + fm) * RS + fk];
        #pragma unroll
        for (int ni = 0; ni < 2; ni++)
            wf[ni] = *(const bf16x8*)&Ws[(wn + ni * 16 + fm) * RS + fk];
        #pragma unroll
        for (int mi = 0; mi < 4; mi++)
            #pragma unroll
            for (int ni = 0; ni < 2; ni++)
                acc[mi][ni] = __builtin_amdgcn_mfma_f32_16x16x32_bf16(
                    af[mi], wf[ni], acc[mi][ni], 0, 0, 0);
        __syncthreads();
    }

    // C/D layout: col = lane&15, row = (lane>>4)*4 + reg
    const int rb = (lane >> 4) * 4;
    const int cc = lane & 15;
    #pragma unroll
    for (int mi = 0; mi < 4; mi++) {
        #pragma unroll
        for (int r = 0; r < 4; r++) {
            int gm = m0 + wm + mi * 16 + rb + r;
            int om = gm;
            if (FLIP) {
                int b = gm / SEQ, l = gm % SEQ;
                om = b * SEQ + (SEQ - 1 - l);
            }
            #pragma unroll
            for (int ni = 0; ni < 2; ni++) {
                int gn = n0 + wn + ni * 16 + cc;
                if (gn < N) {
                    float v = acc[mi][ni][r];
                    if (ACT == 1) v = softplus_fast(v + bias[gn]);
                    stf(C, (size_t)om * ldc + gn, v);
                }
            }
        }
    }
}

// conv + silu; writes fp32 xc (for scan) and bf16 xcb (for x_proj MFMA)
__global__ __launch_bounds__(256) void conv_silu_kernel(
    const float* __restrict__ xz, const float* __restrict__ conv_w,
    const float* __restrict__ conv_b, float* __restrict__ xc,
    u16* __restrict__ xcb)
{
    int idx = blockIdx.x * 256 + threadIdx.x;
    if (idx >= BSZ * SEQ * DI) return;
    int e = idx & (DI - 1);
    int bl = idx / DI;
    int l = bl & (SEQ - 1);
    float acc = conv_b[e];
    #pragma unroll
    for (int k = 0; k < DC; k++) {
        int ll = l + k - (DC - 1);
        if (ll >= 0)
            acc += conv_w[e * DC + k] * xz[((size_t)(bl - l + ll)) * (2 * DI) + e];
    }
    acc = silu_fast(acc);
    xc[idx] = acc;
    xcb[idx] = f2b(acc);
}

// ---- Chunked scan, n-in-registers. Thread = one e; 16 n-states in VGPRs. ----
__global__ __launch_bounds__(256) void scan_pass1(
    const float* __restrict__ dbl,
    const float* __restrict__ xc,
    const u16*  __restrict__ delta,
    const float* __restrict__ A_log,
    float* __restrict__ Pout, float* __restrict__ Qout)
{
    __shared__ float sB[LC][16];
    const int t = threadIdx.x;
    const int c = blockIdx.x;
    const int b = blockIdx.z;
    const int e = blockIdx.y * 256 + t;
    const int row0 = b * SEQ + c * LC;

    if (t < LC * 4) {
        int row = t >> 2, col = (t & 3) * 4;
        *(f32x4*)&sB[row][col] =
            *(const f32x4*)&dbl[(size_t)(row0 + row) * NDBL + DR + col];
    }

    f32x4 Aen[4], P[4], Q[4];
    #pragma unroll
    for (int g = 0; g < 4; g++) {
        f32x4 a = *(const f32x4*)&A_log[(size_t)e * DS + g * 4];
        #pragma unroll
        for (int j = 0; j < 4; j++) Aen[g][j] = -fexp(a[j]);
        P[g] = f32x4{1.f, 1.f, 1.f, 1.f};
        Q[g] = f32x4{0.f, 0.f, 0.f, 0.f};
    }
    __syncthreads();

    float dv = b2f(delta[(size_t)row0 * DI + e]);
    float xv = xc[(size_t)row0 * DI + e];
    for (int i = 0; i < LC; i++) {
        int ip = (i + 1 < LC) ? (i + 1) : (LC - 1);
        float dvn = b2f(delta[(size_t)(row0 + ip) * DI + e]);
        float xvn = xc[(size_t)(row0 + ip) * DI + e];
        float du = dv * xv;
        #pragma unroll
        for (int g = 0; g < 4; g++) {
            f32x4 Bv = *(const f32x4*)&sB[i][g * 4];
            #pragma unroll
            for (int j = 0; j < 4; j++) {
                float dA = fexp(dv * Aen[g][j]);
                P[g][j] *= dA;
                Q[g][j] = dA * Q[g][j] + du * Bv[j];
            }
        }
        dv = dvn; xv = xvn;
    }
    size_t base = ((size_t)(b * NC + c) * DI + e) * DS;
    #pragma unroll
    for (int g = 0; g < 4; g++) {
        *(f32x4*)&Pout[base + g * 4] = P[g];
        *(f32x4*)&Qout[base + g * 4] = Q[g];
    }
}

__global__ __launch_bounds__(256) void scan_pass2(
    const float* __restrict__ P, const float* __restrict__ Q,
    float* __restrict__ H0)
{
    const int gid = blockIdx.x * 256 + threadIdx.x;
    const int en = gid & (DI * DS - 1);
    const int b = gid >> 15;
    float h = 0.f;
    for (int c = 0; c < NC; c++) {
        size_t idx = ((size_t)(b * NC + c) * DI * DS) + en;
        H0[idx] = h;
        h = P[idx] * h + Q[idx];
    }
}

__global__ __launch_bounds__(256) void scan_pass3(
    const float* __restrict__ dbl,
    const float* __restrict__ xc,
    const float* __restrict__ xz,      // z = cols [DI, 2*DI)
    const u16*  __restrict__ delta,
    const float* __restrict__ A_log,
    const float* __restrict__ Dp,
    const float* __restrict__ H0,
    u16* __restrict__ ybf)
{
    __shared__ float sBC[LC][32];
    const int t = threadIdx.x;
    const int c = blockIdx.x;
    const int b = blockIdx.z;
    const int e = blockIdx.y * 256 + t;
    const int row0 = b * SEQ + c * LC;

    {
        int row = t >> 3, col = (t & 7) * 4;
        *(f32x4*)&sBC[row][col] =
            *(const f32x4*)&dbl[(size_t)(row0 + row) * NDBL + DR + col];
    }

    f32x4 Aen[4], h[4];
    size_t base = ((size_t)(b * NC + c) * DI + e) * DS;
    #pragma unroll
    for (int g = 0; g < 4; g++) {
        f32x4 a = *(const f32x4*)&A_log[(size_t)e * DS + g * 4];
        #pragma unroll
        for (int j = 0; j < 4; j++) Aen[g][j] = -fexp(a[j]);
        h[g] = *(const f32x4*)&H0[base + g * 4];
    }
    const float Dv = Dp[e];
    __syncthreads();

    float dv = b2f(delta[(size_t)row0 * DI + e]);
    float xv = xc[(size_t)row0 * DI + e];
    float zv = xz[(size_t)row0 * (2 * DI) + DI + e];
    for (int i = 0; i < LC; i++) {
        int ip = (i + 1 < LC) ? (i + 1) : (LC - 1);
        float dvn = b2f(delta[(size_t)(row0 + ip) * DI + e]);
        float xvn = xc[(size_t)(row0 + ip) * DI + e];
        float zvn = xz[(size_t)(row0 + ip) * (2 * DI) + DI + e];
        float du = dv * xv;
        f32x4 pv = {0.f, 0.f, 0.f, 0.f};
        #pragma unroll
        for (int g = 0; g < 4; g++) {
            f32x4 Bv = *(const f32x4*)&sBC[i][g * 4];
            f32x4 Cv = *(const f32x4*)&sBC[i][16 + g * 4];
            #pragma unroll
            for (int j = 0; j < 4; j++) {
                float dA = fexp(dv * Aen[g][j]);
                h[g][j] = dA * h[g][j] + du * Bv[j];
                pv[j] += h[g][j] * Cv[j];
            }
        }
        float p = pv[0] + pv[1] + pv[2] + pv[3];
        float y = (p + xv * Dv) * silu_fast(zv);
        ybf[(size_t)(row0 + i) * DI + e] = f2b(y);
        dv = dvn; xv = xvn; zv = zvn;
    }
}

extern "C" void kernel_launch(void* const* d_in, const int* in_sizes, int n_in,
                              void* d_out, int out_size, void* d_ws, size_t ws_size,
                              hipStream_t stream)
{
    const float* x = (const float*)d_in[0];
    const float* merge_w = (const float*)d_in[19];
    float* out = (float*)d_out;

    const int M = BSZ * SEQ;   // 2048

    // workspace layout
    float* ws = (float*)d_ws;
    float* ws_xz  = ws;                                   // M*2DI
    float* ws_xc  = ws_xz  + (size_t)M * 2 * DI;          // M*DI
    float* ws_dbl = ws_xc  + (size_t)M * DI;              // M*NDBL
    float* ws_P   = ws_dbl + (size_t)M * NDBL;            // 2*NC*DI*DS
    float* ws_Q   = ws_P   + (size_t)BSZ * NC * DI * DS;
    float* ws_H0  = ws_Q   + (size_t)BSZ * NC * DI * DS;
    u16* ws_delta = (u16*)(ws_H0 + (size_t)BSZ * NC * DI * DS);  // M*DI
    u16* ws_cat   = ws_delta + (size_t)M * DI;            // M*2DM
    u16* ws_xbf   = ws_cat   + (size_t)M * 2 * DM;        // M*DM
    u16* wbf_in   = ws_xbf   + (size_t)M * DM;            // 2DI*DM (also merge)
    u16* wbf_xp   = wbf_in   + (size_t)2 * DI * DM;       // NDBL*DI
    u16* wbf_dt   = wbf_xp   + (size_t)NDBL * DI;         // DI*DR
    u16* wbf_out  = wbf_dt   + (size_t)DI * DR;           // DM*DI
    u16* ws_xcb   = (u16*)ws_Q;                           // alias (dead before Q written)
    u16* ws_ybf   = (u16*)ws_P;                           // alias (dead before ybf written)

    cvt_f2b_kernel<<<(M * DM / 4 + 255) / 256, 256, 0, stream>>>(x, ws_xbf, M * DM / 4);

    for (int dir = 0; dir < 2; dir++) {
        const float* in_proj  = (const float*)d_in[1 + 9 * dir + 0];
        const float* conv_w   = (const float*)d_in[1 + 9 * dir + 1];
        const float* conv_b   = (const float*)d_in[1 + 9 * dir + 2];
        const float* x_proj   = (const float*)d_in[1 + 9 * dir + 3];
        const float* dt_w     = (const float*)d_in[1 + 9 * dir + 4];
        const float* dt_b     = (const float*)d_in[1 + 9 * dir + 5];
        const float* A_log    = (const float*)d_in[1 + 9 * dir + 6];
        const float* Dp       = (const float*)d_in[1 + 9 * dir + 7];
        const float* out_proj = (const float*)d_in[1 + 9 * dir + 8];

        // 0) convert this direction's weights to bf16 (one dispatch)
        {
            int n0 = 2 * DI * DM / 4, n1 = NDBL * DI / 4, n2 = DI * DR / 4, n3 = DM * DI / 4;
            int total = n0 + n1 + n2 + n3;
            cvt4_kernel<<<(total + 255) / 256, 256, 0, stream>>>(
                in_proj, n0, x_proj, n1, dt_w, n2, out_proj, n3,
                wbf_in, wbf_xp, wbf_dt, wbf_out);
        }

        // 1) xz = x @ in_proj^T (bwd: flip output rows)
        {
            dim3 grid((2 * DI) / 64, M / 128);
            if (dir == 0)
                mfma_gemm<u16, float, 0, false><<<grid, 256, 0, stream>>>(
                    ws_xbf, DM, wbf_in, DM, nullptr, ws_xz, 2 * DI, M, 2 * DI, DM);
            else
                mfma_gemm<u16, float, 0, true><<<grid, 256, 0, stream>>>(
                    ws_xbf, DM, wbf_in, DM, nullptr, ws_xz, 2 * DI, M, 2 * DI, DM);
        }

        // 2) conv + silu
        conv_silu_kernel<<<(M * DI) / 256, 256, 0, stream>>>(
            ws_xz, conv_w, conv_b, ws_xc, ws_xcb);

        // 3) dbl = xc @ x_proj^T  (N=96)
        {
            dim3 grid(2, M / 128);
            mfma_gemm<u16, float, 0, false><<<grid, 256, 0, stream>>>(
                ws_xcb, DI, wbf_xp, DI, nullptr, ws_dbl, NDBL, M, NDBL, DI);
        }

        // 4) delta = softplus(dt @ dt_w^T + dt_b) -> bf16  (K=64 MFMA)
        {
            dim3 grid(DI / 64, M / 128);
            mfma_gemm<float, u16, 1, false><<<grid, 256, 0, stream>>>(
                ws_dbl, NDBL, wbf_dt, DR, dt_b, ws_delta, DI, M, DI, DR);
        }

        // 5) chunked scan (n-in-registers)
        {
            dim3 grid(NC, DI / 256, BSZ);
            scan_pass1<<<grid, 256, 0, stream>>>(ws_dbl, ws_xc, ws_delta, A_log, ws_P, ws_Q);
            scan_pass2<<<(BSZ * DI * DS) / 256, 256, 0, stream>>>(ws_P, ws_Q, ws_H0);
            scan_pass3<<<grid, 256, 0, stream>>>(ws_dbl, ws_xc, ws_xz, ws_delta,
                                                 A_log, Dp, ws_H0, ws_ybf);
        }

        // 6) cat[:, dir*DM:+DM] = y @ out_proj^T (bwd: flip rows back)
        {
            dim3 grid(DM / 64, M / 128);
            if (dir == 0)
                mfma_gemm<u16, u16, 0, false><<<grid, 256, 0, stream>>>(
                    ws_ybf, DI, wbf_out, DI, nullptr, ws_cat, 2 * DM, M, DM, DI);
            else
                mfma_gemm<u16, u16, 0, true><<<grid, 256, 0, stream>>>(
                    ws_ybf, DI, wbf_out, DI, nullptr, ws_cat + DM, 2 * DM, M, DM, DI);
        }
    }

    // 7) out = cat @ merge_w^T (fp32 out); merge weights reuse wbf_in
    cvt_f2b_kernel<<<(DM * 2 * DM / 4 + 255) / 256, 256, 0, stream>>>(
        merge_w, wbf_in, DM * 2 * DM / 4);
    {
        dim3 grid(DM / 64, M / 128);
        mfma_gemm<u16, float, 0, false><<<grid, 256, 0, stream>>>(
            ws_cat, 2 * DM, wbf_in, 2 * DM, nullptr, out, DM, M, DM, 2 * DM);
    }
}

// Round 8
// 530.929 us; speedup vs baseline: 6.7767x; 1.1372x over previous
//
#include <hip/hip_runtime.h>
#include <math.h>

#define BSZ 2
#define SEQ 1024
#define DM  1024          // d_model
#define DI  2048          // d_inner
#define DS  16            // d_state
#define DC  4             // d_conv
#define DR  64            // dt_rank
#define NDBL 96           // DR + 2*DS
#define NC  32            // scan chunks
#define LC  32            // SEQ / NC

typedef unsigned short u16;
typedef __bf16 bf16x8 __attribute__((ext_vector_type(8)));
typedef float  f32x4  __attribute__((ext_vector_type(4)));

__device__ __forceinline__ u16 f2b(float f) {
    unsigned int u = __float_as_uint(f);
    unsigned int r = (u + 0x7fffu + ((u >> 16) & 1u)) >> 16;
    return (u16)r;
}
__device__ __forceinline__ float b2f(u16 h) {
    return __uint_as_float(((unsigned int)h) << 16);
}

__device__ __forceinline__ void stf(float* p, size_t i, float v) { p[i] = v; }
__device__ __forceinline__ void stf(u16* p, size_t i, float v)   { p[i] = f2b(v); }

// ---- fast transcendentals ----
__device__ __forceinline__ float fexp(float x)  { return __expf(x); }
__device__ __forceinline__ float frcp(float x)  { return __builtin_amdgcn_rcpf(x); }
__device__ __forceinline__ float silu_fast(float x) {
    return x * frcp(1.f + fexp(-x));
}
__device__ __forceinline__ float softplus_fast(float x) {
    return (x > 15.f) ? x : __logf(1.f + fexp(x));
}

// ---- async global->LDS, 16B per lane; dest = wave-uniform base + lane*16 ----
__device__ __forceinline__ void async16(const u16* g, u16* l) {
    __builtin_amdgcn_global_load_lds(
        (const __attribute__((address_space(1))) void*)g,
        (__attribute__((address_space(3))) void*)l, 16, 0, 0);
}

// XOR-swizzle: 16B-slot for (row, 8-elem chunk j) — 2-way bank aliasing only.
__device__ __forceinline__ int lds_slot(int row, int j) {
    return row * 4 + ((j + (row >> 1)) & 3);
}

// ---- staging helper for fp32 A: 8 floats -> 8 bf16 at LDS slot ----
__device__ __forceinline__ void stage8f(const float* p, u16* d) {
    float4 v0 = *(const float4*)p;
    float4 v1 = *(const float4*)(p + 4);
    ushort4 a; a.x = f2b(v0.x); a.y = f2b(v0.y); a.z = f2b(v0.z); a.w = f2b(v0.w);
    ushort4 b; b.x = f2b(v1.x); b.y = f2b(v1.y); b.z = f2b(v1.z); b.w = f2b(v1.w);
    *(ushort4*)d = a;
    *(ushort4*)(d + 4) = b;
}

// fp32 -> bf16 pack, 4 elems/thread.
__global__ __launch_bounds__(256) void cvt_f2b_kernel(
    const float* __restrict__ in, u16* __restrict__ out, int n4)
{
    int i = blockIdx.x * 256 + threadIdx.x;
    if (i >= n4) return;
    float4 v = ((const float4*)in)[i];
    ushort4 o; o.x = f2b(v.x); o.y = f2b(v.y); o.z = f2b(v.z); o.w = f2b(v.w);
    ((ushort4*)out)[i] = o;
}

// 4-segment fused weight convert (sizes in float4 units)
__global__ __launch_bounds__(256) void cvt4_kernel(
    const float* __restrict__ s0, int n0, const float* __restrict__ s1, int n1,
    const float* __restrict__ s2, int n2, const float* __restrict__ s3, int n3,
    u16* __restrict__ d0, u16* __restrict__ d1,
    u16* __restrict__ d2, u16* __restrict__ d3)
{
    int i = blockIdx.x * 256 + threadIdx.x;
    const float* s; u16* d;
    if (i < n0) { s = s0; d = d0; }
    else if ((i -= n0) < n1) { s = s1; d = d1; }
    else if ((i -= n1) < n2) { s = s2; d = d2; }
    else if ((i -= n2) < n3) { s = s3; d = d3; }
    else return;
    float4 v = ((const float4*)s)[i];
    ushort4 o; o.x = f2b(v.x); o.y = f2b(v.y); o.z = f2b(v.z); o.w = f2b(v.w);
    ((ushort4*)d)[i] = o;
}

// ---------------- MFMA GEMM: C[M,N] = act(A[M,K] @ W[N,K]^T + bias) --------
// Tile 128(M) x 64(N), BK=32, 256 threads = 4 waves (2x2), wave tile 64x32.
// A: u16 (async DMA staging) or fp32 (VALU-converted staging). W: u16.
// LDS: unpadded 32-u16 rows in XOR-swizzled 16B-slot order.
// SPLITK: blockIdx.z halves K and writes fp32 partial plane z (C += z*M*ldc).
template <typename TA, typename TC, int ACT, bool FLIP, bool SPLITK>
__global__ __launch_bounds__(256) void mfma_gemm(
    const TA* __restrict__ A, int lda,
    const u16* __restrict__ W, int ldw,
    const float* __restrict__ bias,
    TC* __restrict__ C, int ldc,
    int M, int N, int K)
{
    __shared__ u16 As[128 * 32];
    __shared__ u16 Ws[64 * 32];

    const int t = threadIdx.x;
    const int wave = t >> 6;
    const int lane = t & 63;
    const int wm = (wave & 1) * 64;
    const int wn = (wave >> 1) * 32;
    const int fm = lane & 15;
    const int q  = lane >> 4;          // k-chunk for fragments
    const int m0 = blockIdx.y * 128;
    const int n0 = blockIdx.x * 64;

    int kbeg = 0, kend = K;
    if (SPLITK) {
        int half = K >> 1;
        kbeg = blockIdx.z * half;
        kend = kbeg + half;
        C += (size_t)blockIdx.z * M * ldc;
    }

    f32x4 acc[4][2] = {};

    for (int k0 = kbeg; k0 < kend; k0 += 32) {
        if constexpr (__is_same(TA, u16)) {
            // A tile: 512 chunks; 2 DMA passes of 256 (1/wave-lane each)
            #pragma unroll
            for (int p = 0; p < 2; p++) {
                int i = p * 256 + wave * 64 + lane;
                int r = i >> 2;
                int j = ((i & 3) - (r >> 1)) & 3;
                async16(A + (size_t)(m0 + r) * lda + k0 + j * 8,
                        &As[(size_t)(p * 256 + wave * 64) * 8]);
            }
        } else {
            // fp32 A: VALU convert into same swizzled layout
            #pragma unroll
            for (int p = 0; p < 2; p++) {
                int i = p * 256 + t;
                int r = i >> 2;
                int j = ((i & 3) - (r >> 1)) & 3;
                stage8f(A + (size_t)(m0 + r) * lda + k0 + j * 8, &As[(size_t)i * 8]);
            }
        }
        {   // W tile: 256 chunks = 64 rows, 1 DMA pass
            int i = wave * 64 + lane;
            int r = i >> 2;
            int j = ((i & 3) - (r >> 1)) & 3;
            int gr = n0 + r;
            if (gr >= N) gr = N - 1;   // clamp (junk cols discarded at store)
            async16(W + (size_t)gr * ldw + k0 + j * 8,
                    &Ws[(size_t)(wave * 64) * 8]);
        }
        __syncthreads();

        bf16x8 af[4], wf[2];
        #pragma unroll
        for (int mi = 0; mi < 4; mi++)
            af[mi] = *(const bf16x8*)&As[(size_t)lds_slot(wm + mi * 16 + fm, q) * 8];
        #pragma unroll
        for (int ni = 0; ni < 2; ni++)
            wf[ni] = *(const bf16x8*)&Ws[(size_t)lds_slot(wn + ni * 16 + fm, q) * 8];
        #pragma unroll
        for (int mi = 0; mi < 4; mi++)
            #pragma unroll
            for (int ni = 0; ni < 2; ni++)
                acc[mi][ni] = __builtin_amdgcn_mfma_f32_16x16x32_bf16(
                    af[mi], wf[ni], acc[mi][ni], 0, 0, 0);
        __syncthreads();
    }

    // C/D layout: col = lane&15, row = (lane>>4)*4 + reg
    const int rb = q * 4;
    const int cc = fm;
    #pragma unroll
    for (int mi = 0; mi < 4; mi++) {
        #pragma unroll
        for (int r = 0; r < 4; r++) {
            int gm = m0 + wm + mi * 16 + rb + r;
            int om = gm;
            if (FLIP) {
                int b = gm / SEQ, l = gm % SEQ;
                om = b * SEQ + (SEQ - 1 - l);
            }
            #pragma unroll
            for (int ni = 0; ni < 2; ni++) {
                int gn = n0 + wn + ni * 16 + cc;
                if (gn < N) {
                    float v = acc[mi][ni][r];
                    if (ACT == 1) v = softplus_fast(v + bias[gn]);
                    stf(C, (size_t)om * ldc + gn, v);
                }
            }
        }
    }
}

// combine split-K partials -> bf16 cat column block
__global__ __launch_bounds__(256) void combine_cat_kernel(
    const float* __restrict__ p0, u16* __restrict__ cat)
{
    int i4 = blockIdx.x * 256 + threadIdx.x;          // over M*DM/4
    const float* p1 = p0 + (size_t)BSZ * SEQ * DM;
    f32x4 a = *(const f32x4*)&p0[(size_t)i4 * 4];
    f32x4 b = *(const f32x4*)&p1[(size_t)i4 * 4];
    int m = i4 >> 8;            // DM/4 = 256 float4 per row
    int n4 = i4 & 255;
    ushort4 o;
    o.x = f2b(a[0] + b[0]); o.y = f2b(a[1] + b[1]);
    o.z = f2b(a[2] + b[2]); o.w = f2b(a[3] + b[3]);
    *(ushort4*)&cat[(size_t)m * 2 * DM + n4 * 4] = o;
}

// combine split-K partials -> fp32 out
__global__ __launch_bounds__(256) void combine_out_kernel(
    const float* __restrict__ p0, float* __restrict__ out)
{
    int i4 = blockIdx.x * 256 + threadIdx.x;
    const float* p1 = p0 + (size_t)BSZ * SEQ * DM;
    f32x4 a = *(const f32x4*)&p0[(size_t)i4 * 4];
    f32x4 b = *(const f32x4*)&p1[(size_t)i4 * 4];
    *(f32x4*)&out[(size_t)i4 * 4] = a + b;
}

// conv + silu; writes fp32 xc (for scan) and bf16 xcb (for x_proj MFMA)
__global__ __launch_bounds__(256) void conv_silu_kernel(
    const float* __restrict__ xz, const float* __restrict__ conv_w,
    const float* __restrict__ conv_b, float* __restrict__ xc,
    u16* __restrict__ xcb)
{
    int idx = blockIdx.x * 256 + threadIdx.x;
    if (idx >= BSZ * SEQ * DI) return;
    int e = idx & (DI - 1);
    int bl = idx / DI;
    int l = bl & (SEQ - 1);
    float acc = conv_b[e];
    #pragma unroll
    for (int k = 0; k < DC; k++) {
        int ll = l + k - (DC - 1);
        if (ll >= 0)
            acc += conv_w[e * DC + k] * xz[((size_t)(bl - l + ll)) * (2 * DI) + e];
    }
    acc = silu_fast(acc);
    xc[idx] = acc;
    xcb[idx] = f2b(acc);
}

// ---- Chunked scan, n-in-registers. Thread = one e; 16 n-states in VGPRs. ----
__global__ __launch_bounds__(256) void scan_pass1(
    const float* __restrict__ dbl,
    const float* __restrict__ xc,
    const u16*  __restrict__ delta,
    const float* __restrict__ A_log,
    float* __restrict__ Pout, float* __restrict__ Qout)
{
    __shared__ float sB[LC][16];
    const int t = threadIdx.x;
    const int c = blockIdx.x;
    const int b = blockIdx.z;
    const int e = blockIdx.y * 256 + t;
    const int row0 = b * SEQ + c * LC;

    if (t < LC * 4) {
        int row = t >> 2, col = (t & 3) * 4;
        *(f32x4*)&sB[row][col] =
            *(const f32x4*)&dbl[(size_t)(row0 + row) * NDBL + DR + col];
    }

    f32x4 Aen[4], P[4], Q[4];
    #pragma unroll
    for (int g = 0; g < 4; g++) {
        f32x4 a = *(const f32x4*)&A_log[(size_t)e * DS + g * 4];
        #pragma unroll
        for (int j = 0; j < 4; j++) Aen[g][j] = -fexp(a[j]);
        P[g] = f32x4{1.f, 1.f, 1.f, 1.f};
        Q[g] = f32x4{0.f, 0.f, 0.f, 0.f};
    }
    __syncthreads();

    float dv = b2f(delta[(size_t)row0 * DI + e]);
    float xv = xc[(size_t)row0 * DI + e];
    for (int i = 0; i < LC; i++) {
        int ip = (i + 1 < LC) ? (i + 1) : (LC - 1);
        float dvn = b2f(delta[(size_t)(row0 + ip) * DI + e]);
        float xvn = xc[(size_t)(row0 + ip) * DI + e];
        float du = dv * xv;
        #pragma unroll
        for (int g = 0; g < 4; g++) {
            f32x4 Bv = *(const f32x4*)&sB[i][g * 4];
            #pragma unroll
            for (int j = 0; j < 4; j++) {
                float dA = fexp(dv * Aen[g][j]);
                P[g][j] *= dA;
                Q[g][j] = dA * Q[g][j] + du * Bv[j];
            }
        }
        dv = dvn; xv = xvn;
    }
    size_t base = ((size_t)(b * NC + c) * DI + e) * DS;
    #pragma unroll
    for (int g = 0; g < 4; g++) {
        *(f32x4*)&Pout[base + g * 4] = P[g];
        *(f32x4*)&Qout[base + g * 4] = Q[g];
    }
}

__global__ __launch_bounds__(256) void scan_pass2(
    const float* __restrict__ P, const float* __restrict__ Q,
    float* __restrict__ H0)
{
    const int gid = blockIdx.x * 256 + threadIdx.x;
    const int en = gid & (DI * DS - 1);
    const int b = gid >> 15;
    float h = 0.f;
    for (int c = 0; c < NC; c++) {
        size_t idx = ((size_t)(b * NC + c) * DI * DS) + en;
        H0[idx] = h;
        h = P[idx] * h + Q[idx];
    }
}

// pass3: replay chunk; writes gated y IN-PLACE over delta (same index, post-read)
__global__ __launch_bounds__(256) void scan_pass3(
    const float* __restrict__ dbl,
    const float* __restrict__ xc,
    const float* __restrict__ xz,      // z = cols [DI, 2*DI)
    u16* delta_y,                      // in: delta, out: y (bf16)
    const float* __restrict__ A_log,
    const float* __restrict__ Dp,
    const float* __restrict__ H0)
{
    __shared__ float sBC[LC][32];
    const int t = threadIdx.x;
    const int c = blockIdx.x;
    const int b = blockIdx.z;
    const int e = blockIdx.y * 256 + t;
    const int row0 = b * SEQ + c * LC;

    {
        int row = t >> 3, col = (t & 7) * 4;
        *(f32x4*)&sBC[row][col] =
            *(const f32x4*)&dbl[(size_t)(row0 + row) * NDBL + DR + col];
    }

    f32x4 Aen[4], h[4];
    size_t base = ((size_t)(b * NC + c) * DI + e) * DS;
    #pragma unroll
    for (int g = 0; g < 4; g++) {
        f32x4 a = *(const f32x4*)&A_log[(size_t)e * DS + g * 4];
        #pragma unroll
        for (int j = 0; j < 4; j++) Aen[g][j] = -fexp(a[j]);
        h[g] = *(const f32x4*)&H0[base + g * 4];
    }
    const float Dv = Dp[e];
    __syncthreads();

    float dv = b2f(delta_y[(size_t)row0 * DI + e]);
    float xv = xc[(size_t)row0 * DI + e];
    float zv = xz[(size_t)row0 * (2 * DI) + DI + e];
    for (int i = 0; i < LC; i++) {
        int ip = (i + 1 < LC) ? (i + 1) : (LC - 1);
        float dvn = b2f(delta_y[(size_t)(row0 + ip) * DI + e]);
        float xvn = xc[(size_t)(row0 + ip) * DI + e];
        float zvn = xz[(size_t)(row0 + ip) * (2 * DI) + DI + e];
        float du = dv * xv;
        f32x4 pv = {0.f, 0.f, 0.f, 0.f};
        #pragma unroll
        for (int g = 0; g < 4; g++) {
            f32x4 Bv = *(const f32x4*)&sBC[i][g * 4];
            f32x4 Cv = *(const f32x4*)&sBC[i][16 + g * 4];
            #pragma unroll
            for (int j = 0; j < 4; j++) {
                float dA = fexp(dv * Aen[g][j]);
                h[g][j] = dA * h[g][j] + du * Bv[j];
                pv[j] += h[g][j] * Cv[j];
            }
        }
        float p = pv[0] + pv[1] + pv[2] + pv[3];
        float y = (p + xv * Dv) * silu_fast(zv);
        delta_y[(size_t)(row0 + i) * DI + e] = f2b(y);
        dv = dvn; xv = xvn; zv = zvn;
    }
}

extern "C" void kernel_launch(void* const* d_in, const int* in_sizes, int n_in,
                              void* d_out, int out_size, void* d_ws, size_t ws_size,
                              hipStream_t stream)
{
    const float* x = (const float*)d_in[0];
    const float* merge_w = (const float*)d_in[19];
    float* out = (float*)d_out;

    const int M = BSZ * SEQ;   // 2048

    // workspace layout
    float* ws = (float*)d_ws;
    float* ws_xz  = ws;                                   // M*2DI
    float* ws_xc  = ws_xz  + (size_t)M * 2 * DI;          // M*DI
    float* ws_dbl = ws_xc  + (size_t)M * DI;              // M*NDBL
    float* ws_P   = ws_dbl + (size_t)M * NDBL;            // B*NC*DI*DS = M*DM
    float* ws_Q   = ws_P   + (size_t)BSZ * NC * DI * DS;  // (contiguous with P)
    float* ws_H0  = ws_Q   + (size_t)BSZ * NC * DI * DS;
    u16* ws_delta = (u16*)(ws_H0 + (size_t)BSZ * NC * DI * DS);  // M*DI (delta -> y)
    u16* ws_cat   = ws_delta + (size_t)M * DI;            // M*2DM
    u16* ws_xbf   = ws_cat   + (size_t)M * 2 * DM;        // M*DM
    u16* wbf_in   = ws_xbf   + (size_t)M * DM;            // 2DI*DM (also merge)
    u16* wbf_xp   = wbf_in   + (size_t)2 * DI * DM;       // NDBL*DI
    u16* wbf_dt   = wbf_xp   + (size_t)NDBL * DI;         // DI*DR
    u16* wbf_out  = wbf_dt   + (size_t)DI * DR;           // DM*DI
    u16* ws_xcb   = (u16*)ws_Q;        // alias: dead before pass1 writes Q
    float* ws_par = ws_P;              // split-K partials (P/Q dead after pass2/3)

    cvt_f2b_kernel<<<(M * DM / 4 + 255) / 256, 256, 0, stream>>>(x, ws_xbf, M * DM / 4);

    for (int dir = 0; dir < 2; dir++) {
        const float* in_proj  = (const float*)d_in[1 + 9 * dir + 0];
        const float* conv_w   = (const float*)d_in[1 + 9 * dir + 1];
        const float* conv_b   = (const float*)d_in[1 + 9 * dir + 2];
        const float* x_proj   = (const float*)d_in[1 + 9 * dir + 3];
        const float* dt_w     = (const float*)d_in[1 + 9 * dir + 4];
        const float* dt_b     = (const float*)d_in[1 + 9 * dir + 5];
        const float* A_log    = (const float*)d_in[1 + 9 * dir + 6];
        const float* Dp       = (const float*)d_in[1 + 9 * dir + 7];
        const float* out_proj = (const float*)d_in[1 + 9 * dir + 8];

        // 0) convert this direction's weights to bf16 (one dispatch)
        {
            int n0 = 2 * DI * DM / 4, n1 = NDBL * DI / 4, n2 = DI * DR / 4, n3 = DM * DI / 4;
            int total = n0 + n1 + n2 + n3;
            cvt4_kernel<<<(total + 255) / 256, 256, 0, stream>>>(
                in_proj, n0, x_proj, n1, dt_w, n2, out_proj, n3,
                wbf_in, wbf_xp, wbf_dt, wbf_out);
        }

        // 1) xz = x @ in_proj^T (bwd: flip output rows)
        {
            dim3 grid((2 * DI) / 64, M / 128);
            if (dir == 0)
                mfma_gemm<u16, float, 0, false, false><<<grid, 256, 0, stream>>>(
                    ws_xbf, DM, wbf_in, DM, nullptr, ws_xz, 2 * DI, M, 2 * DI, DM);
            else
                mfma_gemm<u16, float, 0, true, false><<<grid, 256, 0, stream>>>(
                    ws_xbf, DM, wbf_in, DM, nullptr, ws_xz, 2 * DI, M, 2 * DI, DM);
        }

        // 2) conv + silu
        conv_silu_kernel<<<(M * DI) / 256, 256, 0, stream>>>(
            ws_xz, conv_w, conv_b, ws_xc, ws_xcb);

        // 3) dbl = xc @ x_proj^T  (N=96)
        {
            dim3 grid(2, M / 128);
            mfma_gemm<u16, float, 0, false, false><<<grid, 256, 0, stream>>>(
                ws_xcb, DI, wbf_xp, DI, nullptr, ws_dbl, NDBL, M, NDBL, DI);
        }

        // 4) delta = softplus(dt @ dt_w^T + dt_b) -> bf16  (K=64 MFMA, fp32 A)
        {
            dim3 grid(DI / 64, M / 128);
            mfma_gemm<float, u16, 1, false, false><<<grid, 256, 0, stream>>>(
                ws_dbl, NDBL, wbf_dt, DR, dt_b, ws_delta, DI, M, DI, DR);
        }

        // 5) chunked scan (n-in-registers); pass3 writes y over delta
        {
            dim3 grid(NC, DI / 256, BSZ);
            scan_pass1<<<grid, 256, 0, stream>>>(ws_dbl, ws_xc, ws_delta, A_log, ws_P, ws_Q);
            scan_pass2<<<(BSZ * DI * DS) / 256, 256, 0, stream>>>(ws_P, ws_Q, ws_H0);
            scan_pass3<<<grid, 256, 0, stream>>>(ws_dbl, ws_xc, ws_xz, ws_delta,
                                                 A_log, Dp, ws_H0);
        }

        // 6) cat[:, dir*DM:+DM] = y @ out_proj^T, split-K2 (bwd: flip rows back)
        {
            dim3 grid(DM / 64, M / 128, 2);
            if (dir == 0)
                mfma_gemm<u16, float, 0, false, true><<<grid, 256, 0, stream>>>(
                    ws_delta, DI, wbf_out, DI, nullptr, ws_par, DM, M, DM, DI);
            else
                mfma_gemm<u16, float, 0, true, true><<<grid, 256, 0, stream>>>(
                    ws_delta, DI, wbf_out, DI, nullptr, ws_par, DM, M, DM, DI);
            combine_cat_kernel<<<(M * DM / 4) / 256, 256, 0, stream>>>(
                ws_par, ws_cat + dir * DM);
        }
    }

    // 7) out = cat @ merge_w^T, split-K2 (fp32 out); merge weights reuse wbf_in
    cvt_f2b_kernel<<<(DM * 2 * DM / 4 + 255) / 256, 256, 0, stream>>>(
        merge_w, wbf_in, DM * 2 * DM / 4);
    {
        dim3 grid(DM / 64, M / 128, 2);
        mfma_gemm<u16, float, 0, false, true><<<grid, 256, 0, stream>>>(
            ws_cat, 2 * DM, wbf_in, 2 * DM, nullptr, ws_par, DM, M, DM, 2 * DM);
        combine_out_kernel<<<(M * DM / 4) / 256, 256, 0, stream>>>(ws_par, out);
    }
}

// Round 10
// 424.520 us; speedup vs baseline: 8.4753x; 1.2507x over previous
//
#include <hip/hip_runtime.h>
#include <math.h>

#define BSZ 2
#define SEQ 1024
#define DM  1024          // d_model
#define DI  2048          // d_inner
#define DS  16            // d_state
#define DC  4             // d_conv
#define DR  64            // dt_rank
#define NDBL 96           // DR + 2*DS
#define NC  32            // scan chunks
#define LC  32            // SEQ / NC
#define MM  (BSZ * SEQ)   // 2048 rows

typedef unsigned short u16;
typedef __bf16 bf16x8 __attribute__((ext_vector_type(8)));
typedef float  f32x4  __attribute__((ext_vector_type(4)));

// ---- segment sizes (float4 units) and weight-block offsets (u16 units) ----
constexpr int N4_X   = MM * DM / 4;          //   524,288
constexpr int N4_MW  = DM * 2 * DM / 4;      //   524,288
constexpr int N4_IN  = 2 * DI * DM / 4;      // 1,048,576
constexpr int N4_XP  = NDBL * DI / 4;        //    49,152
constexpr int N4_DT  = DI * DR / 4;          //    32,768
constexpr int N4_OUT = DM * DI / 4;          //   524,288
constexpr int N4_TOTAL = N4_X + N4_MW + 2 * (N4_IN + N4_XP + N4_DT + N4_OUT);
constexpr size_t O_XP  = (size_t)2 * DI * DM;            // 4,194,304
constexpr size_t O_DT  = O_XP + (size_t)NDBL * DI;       // 4,390,912
constexpr size_t O_OUT = O_DT + (size_t)DI * DR;         // 4,521,984
constexpr size_t WBF_SZ = O_OUT + (size_t)DM * DI;       // 6,619,136 u16 per dir

__device__ __forceinline__ u16 f2b(float f) {
    unsigned int u = __float_as_uint(f);
    unsigned int r = (u + 0x7fffu + ((u >> 16) & 1u)) >> 16;
    return (u16)r;
}
__device__ __forceinline__ float b2f(u16 h) {
    return __uint_as_float(((unsigned int)h) << 16);
}

__device__ __forceinline__ void stf(float* p, size_t i, float v) { p[i] = v; }
__device__ __forceinline__ void stf(u16* p, size_t i, float v)   { p[i] = f2b(v); }

// ---- fast transcendentals ----
__device__ __forceinline__ float fexp(float x)  { return __expf(x); }
__device__ __forceinline__ float frcp(float x)  { return __builtin_amdgcn_rcpf(x); }
__device__ __forceinline__ float silu_fast(float x) {
    return x * frcp(1.f + fexp(-x));
}
__device__ __forceinline__ float softplus_fast(float x) {
    return (x > 15.f) ? x : __logf(1.f + fexp(x));
}

// ---- async global->LDS, 16B/lane; dest = wave-uniform base + lane*16 ----
__device__ __forceinline__ void async16(const u16* g, u16* l) {
    __builtin_amdgcn_global_load_lds(
        (const __attribute__((address_space(1))) void*)g,
        (__attribute__((address_space(3))) void*)l, 16, 0, 0);
}

// XOR-swizzle: 16B-slot for (row, 8-elem chunk j) — 2-way bank aliasing only.
__device__ __forceinline__ int lds_slot(int row, int j) {
    return row * 4 + ((j + (row >> 1)) & 3);
}

// ---- staging helper for fp32 A: 8 floats -> 8 bf16 at LDS slot ----
__device__ __forceinline__ void stage8f(const float* p, u16* d) {
    float4 v0 = *(const float4*)p;
    float4 v1 = *(const float4*)(p + 4);
    ushort4 a; a.x = f2b(v0.x); a.y = f2b(v0.y); a.z = f2b(v0.z); a.w = f2b(v0.w);
    ushort4 b; b.x = f2b(v1.x); b.y = f2b(v1.y); b.z = f2b(v1.z); b.w = f2b(v1.w);
    *(ushort4*)d = a;
    *(ushort4*)(d + 4) = b;
}

// ---- one-shot fp32->bf16 convert of x, merge_w, and both dirs' weights ----
__global__ __launch_bounds__(256) void cvt_all_kernel(
    const float* __restrict__ s0, const float* __restrict__ s1,
    const float* __restrict__ s2, const float* __restrict__ s3,
    const float* __restrict__ s4, const float* __restrict__ s5,
    const float* __restrict__ s6, const float* __restrict__ s7,
    const float* __restrict__ s8, const float* __restrict__ s9,
    u16* __restrict__ d0, u16* __restrict__ d1, u16* __restrict__ d2,
    u16* __restrict__ d3, u16* __restrict__ d4, u16* __restrict__ d5,
    u16* __restrict__ d6, u16* __restrict__ d7, u16* __restrict__ d8,
    u16* __restrict__ d9)
{
    int i = blockIdx.x * 256 + threadIdx.x;
    const float* s; u16* d;
    if (i < N4_X) { s = s0; d = d0; }                    // x
    else if ((i -= N4_X) < N4_MW) { s = s1; d = d1; }    // merge_w
    else if ((i -= N4_MW) < N4_IN) { s = s2; d = d2; }   // in0
    else if ((i -= N4_IN) < N4_XP) { s = s3; d = d3; }   // xp0
    else if ((i -= N4_XP) < N4_DT) { s = s4; d = d4; }   // dt0
    else if ((i -= N4_DT) < N4_OUT) { s = s5; d = d5; }  // out0
    else if ((i -= N4_OUT) < N4_IN) { s = s6; d = d6; }  // in1
    else if ((i -= N4_IN) < N4_XP) { s = s7; d = d7; }   // xp1
    else if ((i -= N4_XP) < N4_DT) { s = s8; d = d8; }   // dt1
    else if ((i -= N4_DT) < N4_OUT) { s = s9; d = d9; }  // out1
    else return;
    float4 v = ((const float4*)s)[i];
    ushort4 o; o.x = f2b(v.x); o.y = f2b(v.y); o.z = f2b(v.z); o.w = f2b(v.w);
    ((ushort4*)d)[i] = o;
}

// ---------------- dual-direction MFMA GEMM --------------------------------
// C[M,N] = act(A[M,K] @ W[N,K]^T + bias). Tile 128x64, BK=32, 4 waves (2x2).
// blockIdx.z = dir*NSPLIT + split (DUAL) or split (non-dual).
// NSPLIT>1: TC must be float; C = plane base + split*M*ldc (fp32 partials).
// FLIP1: dir-1 output rows are flipped within each batch's SEQ rows.
template <typename TA, typename TC, int ACT, bool DUAL, bool FLIP1, int NSPLIT>
__global__ __launch_bounds__(256) void mfma_gemm(
    const TA* __restrict__ A0, const TA* __restrict__ A1, int lda,
    const u16* __restrict__ W0, const u16* __restrict__ W1, int ldw,
    const float* __restrict__ bias0, const float* __restrict__ bias1,
    TC* __restrict__ C0, TC* __restrict__ C1, int ldc,
    int M, int N, int K)
{
    __shared__ u16 As[128 * 32];
    __shared__ u16 Ws[64 * 32];

    const int z = blockIdx.z;
    const int dir = DUAL ? (z / NSPLIT) : 0;
    const int split = z % NSPLIT;
    const TA* A = dir ? A1 : A0;
    const u16* W = dir ? W1 : W0;
    const float* bias = dir ? bias1 : bias0;
    TC* C = dir ? C1 : C0;
    if (NSPLIT > 1) C += (size_t)split * M * ldc;
    const int kseg = K / NSPLIT;
    const int kbeg = split * kseg, kend = kbeg + kseg;

    const int t = threadIdx.x;
    const int wave = t >> 6;
    const int lane = t & 63;
    const int wm = (wave & 1) * 64;
    const int wn = (wave >> 1) * 32;
    const int fm = lane & 15;
    const int q  = lane >> 4;
    const int m0 = blockIdx.y * 128;
    const int n0 = blockIdx.x * 64;

    f32x4 acc[4][2] = {};

    for (int k0 = kbeg; k0 < kend; k0 += 32) {
        if constexpr (__is_same(TA, u16)) {
            #pragma unroll
            for (int p = 0; p < 2; p++) {
                int i = p * 256 + wave * 64 + lane;
                int r = i >> 2;
                int j = ((i & 3) - (r >> 1)) & 3;
                async16(A + (size_t)(m0 + r) * lda + k0 + j * 8,
                        &As[(size_t)(p * 256 + wave * 64) * 8]);
            }
        } else {
            #pragma unroll
            for (int p = 0; p < 2; p++) {
                int i = p * 256 + t;
                int r = i >> 2;
                int j = ((i & 3) - (r >> 1)) & 3;
                stage8f(A + (size_t)(m0 + r) * lda + k0 + j * 8, &As[(size_t)i * 8]);
            }
        }
        {
            int i = wave * 64 + lane;
            int r = i >> 2;
            int j = ((i & 3) - (r >> 1)) & 3;
            int gr = n0 + r;
            if (gr >= N) gr = N - 1;   // clamp (junk discarded at store)
            async16(W + (size_t)gr * ldw + k0 + j * 8,
                    &Ws[(size_t)(wave * 64) * 8]);
        }
        __syncthreads();

        bf16x8 af[4], wf[2];
        #pragma unroll
        for (int mi = 0; mi < 4; mi++)
            af[mi] = *(const bf16x8*)&As[(size_t)lds_slot(wm + mi * 16 + fm, q) * 8];
        #pragma unroll
        for (int ni = 0; ni < 2; ni++)
            wf[ni] = *(const bf16x8*)&Ws[(size_t)lds_slot(wn + ni * 16 + fm, q) * 8];
        #pragma unroll
        for (int mi = 0; mi < 4; mi++)
            #pragma unroll
            for (int ni = 0; ni < 2; ni++)
                acc[mi][ni] = __builtin_amdgcn_mfma_f32_16x16x32_bf16(
                    af[mi], wf[ni], acc[mi][ni], 0, 0, 0);
        __syncthreads();
    }

    // C/D layout: col = lane&15, row = (lane>>4)*4 + reg
    const int rb = q * 4;
    const int cc = fm;
    #pragma unroll
    for (int mi = 0; mi < 4; mi++) {
        #pragma unroll
        for (int r = 0; r < 4; r++) {
            int gm = m0 + wm + mi * 16 + rb + r;
            int om = gm;
            if (FLIP1 && dir == 1) {
                int bb = gm / SEQ, l = gm % SEQ;
                om = bb * SEQ + (SEQ - 1 - l);
            }
            #pragma unroll
            for (int ni = 0; ni < 2; ni++) {
                int gn = n0 + wn + ni * 16 + cc;
                if (gn < N) {
                    float v = acc[mi][ni][r];
                    if (ACT == 1) v = softplus_fast(v + bias[gn]);
                    stf(C, (size_t)om * ldc + gn, v);
                }
            }
        }
    }
}

// ---- split-K combines ----
__global__ __launch_bounds__(256) void combine_dbl_kernel(
    const float* __restrict__ par, float* __restrict__ dbl)
{
    int i4 = blockIdx.x * 256 + threadIdx.x;   // [0, 2*MM*NDBL/4)
    const int per = (MM * NDBL) / 4;           // 49152
    int dir = (i4 >= per) ? 1 : 0;
    int j4 = i4 - dir * per;
    const float* p = par + (size_t)dir * 4 * MM * NDBL;
    f32x4 s = {0.f, 0.f, 0.f, 0.f};
    #pragma unroll
    for (int k = 0; k < 4; k++)
        s += *(const f32x4*)&p[(size_t)k * MM * NDBL + (size_t)j4 * 4];
    *(f32x4*)&dbl[(size_t)dir * MM * NDBL + (size_t)j4 * 4] = s;
}

__global__ __launch_bounds__(256) void combine_cat_kernel(
    const float* __restrict__ par, u16* __restrict__ cat)
{
    int i4 = blockIdx.x * 256 + threadIdx.x;   // [0, 2*MM*DM/4)
    const int per = (MM * DM) / 4;             // 524288
    int dir = (i4 >= per) ? 1 : 0;
    int j4 = i4 - dir * per;
    const float* p0 = par + (size_t)dir * 2 * MM * DM;
    const float* p1 = p0 + (size_t)MM * DM;
    f32x4 a = *(const f32x4*)&p0[(size_t)j4 * 4];
    f32x4 b = *(const f32x4*)&p1[(size_t)j4 * 4];
    int m = j4 >> 8;           // DM/4 = 256 float4 per row
    int n4 = j4 & 255;
    ushort4 o;
    o.x = f2b(a[0] + b[0]); o.y = f2b(a[1] + b[1]);
    o.z = f2b(a[2] + b[2]); o.w = f2b(a[3] + b[3]);
    *(ushort4*)&cat[(size_t)m * 2 * DM + dir * DM + n4 * 4] = o;
}

__global__ __launch_bounds__(256) void combine_out_kernel(
    const float* __restrict__ p0, float* __restrict__ out)
{
    int i4 = blockIdx.x * 256 + threadIdx.x;   // [0, MM*DM/4)
    const float* p1 = p0 + (size_t)MM * DM;
    f32x4 a = *(const f32x4*)&p0[(size_t)i4 * 4];
    f32x4 b = *(const f32x4*)&p1[(size_t)i4 * 4];
    *(f32x4*)&out[(size_t)i4 * 4] = a + b;
}

// ---- conv + silu, both dirs; writes fp32 xc and bf16 xcb ----
__global__ __launch_bounds__(256) void conv_silu_kernel(
    const float* __restrict__ xz,
    const float* __restrict__ cw0, const float* __restrict__ cw1,
    const float* __restrict__ cb0, const float* __restrict__ cb1,
    float* __restrict__ xc, u16* __restrict__ xcb)
{
    int idx = blockIdx.x * 256 + threadIdx.x;   // [0, 2*MM*DI)
    int dir = (idx >= MM * DI) ? 1 : 0;
    int rem = idx - dir * MM * DI;
    int e = rem & (DI - 1);
    int bl = rem / DI;
    int l = bl & (SEQ - 1);
    const float* xz_d = xz + (size_t)dir * MM * 2 * DI;
    const float* cw = dir ? cw1 : cw0;
    const float* cb = dir ? cb1 : cb0;
    float acc = cb[e];
    #pragma unroll
    for (int k = 0; k < DC; k++) {
        int ll = l + k - (DC - 1);
        if (ll >= 0)
            acc += cw[e * DC + k] * xz_d[((size_t)(bl - l + ll)) * (2 * DI) + e];
    }
    acc = silu_fast(acc);
    xc[idx] = acc;
    xcb[idx] = f2b(acc);
}

// ---- Chunked scan, both dirs, n-in-registers ----
// grid (NC, DI/256, 2*BSZ); z: dir = z>>1, b = z&1.
__global__ __launch_bounds__(256) void scan_pass1(
    const float* __restrict__ dbl,
    const float* __restrict__ xc,
    const u16*  __restrict__ delta,
    const float* __restrict__ Alog0, const float* __restrict__ Alog1,
    float* __restrict__ Pout, float* __restrict__ Qout)
{
    __shared__ float sB[LC][16];
    const int t = threadIdx.x;
    const int c = blockIdx.x;
    const int dir = blockIdx.z >> 1;
    const int b = blockIdx.z & 1;
    const int e = blockIdx.y * 256 + t;
    const int row0 = b * SEQ + c * LC;
    const float* dbl_d = dbl + (size_t)dir * MM * NDBL;
    const float* xc_d = xc + (size_t)dir * MM * DI;
    const u16* delta_d = delta + (size_t)dir * MM * DI;
    const float* A_log = dir ? Alog1 : Alog0;
    float* P_d = Pout + (size_t)dir * BSZ * NC * DI * DS;
    float* Q_d = Qout + (size_t)dir * BSZ * NC * DI * DS;

    if (t < LC * 4) {
        int row = t >> 2, col = (t & 3) * 4;
        *(f32x4*)&sB[row][col] =
            *(const f32x4*)&dbl_d[(size_t)(row0 + row) * NDBL + DR + col];
    }

    f32x4 Aen[4], P[4], Q[4];
    #pragma unroll
    for (int g = 0; g < 4; g++) {
        f32x4 a = *(const f32x4*)&A_log[(size_t)e * DS + g * 4];
        #pragma unroll
        for (int j = 0; j < 4; j++) Aen[g][j] = -fexp(a[j]);
        P[g] = f32x4{1.f, 1.f, 1.f, 1.f};
        Q[g] = f32x4{0.f, 0.f, 0.f, 0.f};
    }
    __syncthreads();

    float dv = b2f(delta_d[(size_t)row0 * DI + e]);
    float xv = xc_d[(size_t)row0 * DI + e];
    for (int i = 0; i < LC; i++) {
        int ip = (i + 1 < LC) ? (i + 1) : (LC - 1);
        float dvn = b2f(delta_d[(size_t)(row0 + ip) * DI + e]);
        float xvn = xc_d[(size_t)(row0 + ip) * DI + e];
        float du = dv * xv;
        #pragma unroll
        for (int g = 0; g < 4; g++) {
            f32x4 Bv = *(const f32x4*)&sB[i][g * 4];
            #pragma unroll
            for (int j = 0; j < 4; j++) {
                float dA = fexp(dv * Aen[g][j]);
                P[g][j] *= dA;
                Q[g][j] = dA * Q[g][j] + du * Bv[j];
            }
        }
        dv = dvn; xv = xvn;
    }
    size_t base = ((size_t)(b * NC + c) * DI + e) * DS;
    #pragma unroll
    for (int g = 0; g < 4; g++) {
        *(f32x4*)&P_d[base + g * 4] = P[g];
        *(f32x4*)&Q_d[base + g * 4] = Q[g];
    }
}

__global__ __launch_bounds__(256) void scan_pass2(
    const float* __restrict__ P, const float* __restrict__ Q,
    float* __restrict__ H0)
{
    const int gid = blockIdx.x * 256 + threadIdx.x;  // [0, 2*BSZ*DI*DS)
    const int dir = gid >> 16;
    const int loc = gid & 65535;
    const int b = loc >> 15;
    const int en = loc & (DI * DS - 1);
    size_t doff = (size_t)dir * BSZ * NC * DI * DS;
    float h = 0.f;
    for (int c = 0; c < NC; c++) {
        size_t idx = doff + ((size_t)(b * NC + c) * DI * DS) + en;
        H0[idx] = h;
        h = P[idx] * h + Q[idx];
    }
}

// pass3: replay chunk; writes gated y IN-PLACE over delta
__global__ __launch_bounds__(256) void scan_pass3(
    const float* __restrict__ dbl,
    const float* __restrict__ xc,
    const float* __restrict__ xz,
    u16* delta_y,
    const float* __restrict__ Alog0, const float* __restrict__ Alog1,
    const float* __restrict__ Dp0, const float* __restrict__ Dp1,
    const float* __restrict__ H0)
{
    __shared__ float sBC[LC][32];
    const int t = threadIdx.x;
    const int c = blockIdx.x;
    const int dir = blockIdx.z >> 1;
    const int b = blockIdx.z & 1;
    const int e = blockIdx.y * 256 + t;
    const int row0 = b * SEQ + c * LC;
    const float* dbl_d = dbl + (size_t)dir * MM * NDBL;
    const float* xc_d = xc + (size_t)dir * MM * DI;
    const float* xz_d = xz + (size_t)dir * MM * 2 * DI;
    u16* dy_d = delta_y + (size_t)dir * MM * DI;
    const float* A_log = dir ? Alog1 : Alog0;
    const float* Dp = dir ? Dp1 : Dp0;
    const float* H0_d = H0 + (size_t)dir * BSZ * NC * DI * DS;

    {
        int row = t >> 3, col = (t & 7) * 4;
        *(f32x4*)&sBC[row][col] =
            *(const f32x4*)&dbl_d[(size_t)(row0 + row) * NDBL + DR + col];
    }

    f32x4 Aen[4], h[4];
    size_t base = ((size_t)(b * NC + c) * DI + e) * DS;
    #pragma unroll
    for (int g = 0; g < 4; g++) {
        f32x4 a = *(const f32x4*)&A_log[(size_t)e * DS + g * 4];
        #pragma unroll
        for (int j = 0; j < 4; j++) Aen[g][j] = -fexp(a[j]);
        h[g] = *(const f32x4*)&H0_d[base + g * 4];
    }
    const float Dv = Dp[e];
    __syncthreads();

    float dv = b2f(dy_d[(size_t)row0 * DI + e]);
    float xv = xc_d[(size_t)row0 * DI + e];
    float zv = xz_d[(size_t)row0 * (2 * DI) + DI + e];
    for (int i = 0; i < LC; i++) {
        int ip = (i + 1 < LC) ? (i + 1) : (LC - 1);
        float dvn = b2f(dy_d[(size_t)(row0 + ip) * DI + e]);
        float xvn = xc_d[(size_t)(row0 + ip) * DI + e];
        float zvn = xz_d[(size_t)(row0 + ip) * (2 * DI) + DI + e];
        float du = dv * xv;
        f32x4 pv = {0.f, 0.f, 0.f, 0.f};
        #pragma unroll
        for (int g = 0; g < 4; g++) {
            f32x4 Bv = *(const f32x4*)&sBC[i][g * 4];
            f32x4 Cv = *(const f32x4*)&sBC[i][16 + g * 4];
            #pragma unroll
            for (int j = 0; j < 4; j++) {
                float dA = fexp(dv * Aen[g][j]);
                h[g][j] = dA * h[g][j] + du * Bv[j];
                pv[j] += h[g][j] * Cv[j];
            }
        }
        float p = pv[0] + pv[1] + pv[2] + pv[3];
        float y = (p + xv * Dv) * silu_fast(zv);
        dy_d[(size_t)(row0 + i) * DI + e] = f2b(y);
        dv = dvn; xv = xvn; zv = zvn;
    }
}

extern "C" void kernel_launch(void* const* d_in, const int* in_sizes, int n_in,
                              void* d_out, int out_size, void* d_ws, size_t ws_size,
                              hipStream_t stream)
{
    const float* x = (const float*)d_in[0];
    const float* in_p[2]  = {(const float*)d_in[1],  (const float*)d_in[10]};
    const float* conv_w[2]= {(const float*)d_in[2],  (const float*)d_in[11]};
    const float* conv_b[2]= {(const float*)d_in[3],  (const float*)d_in[12]};
    const float* x_p[2]   = {(const float*)d_in[4],  (const float*)d_in[13]};
    const float* dt_w[2]  = {(const float*)d_in[5],  (const float*)d_in[14]};
    const float* dt_b[2]  = {(const float*)d_in[6],  (const float*)d_in[15]};
    const float* A_log[2] = {(const float*)d_in[7],  (const float*)d_in[16]};
    const float* Dp[2]    = {(const float*)d_in[8],  (const float*)d_in[17]};
    const float* out_p[2] = {(const float*)d_in[9],  (const float*)d_in[18]};
    const float* merge_w  = (const float*)d_in[19];
    float* out = (float*)d_out;

    // ---- workspace layout (element units) ----
    float* ws = (float*)d_ws;
    float* ws_xz  = ws;                                    // 2 * MM*2DI f
    float* ws_xc  = ws_xz  + (size_t)2 * MM * 2 * DI;      // 2 * MM*DI f
    float* ws_dbl = ws_xc  + (size_t)2 * MM * DI;          // 2 * MM*NDBL f
    float* ws_P   = ws_dbl + (size_t)2 * MM * NDBL;        // 2 * BSZ*NC*DI*DS f
    float* ws_Q   = ws_P   + (size_t)2 * BSZ * NC * DI * DS;
    float* ws_H0  = ws_Q   + (size_t)2 * BSZ * NC * DI * DS;
    u16* ws_delta = (u16*)(ws_H0 + (size_t)2 * BSZ * NC * DI * DS); // 2*MM*DI u16
    u16* ws_cat   = ws_delta + (size_t)2 * MM * DI;        // MM*2DM u16
    u16* ws_xbf   = ws_cat   + (size_t)MM * 2 * DM;        // MM*DM u16
    u16* wbf_mw   = ws_xbf   + (size_t)MM * DM;            // DM*2DM u16
    u16* wbf0     = wbf_mw   + (size_t)DM * 2 * DM;        // WBF_SZ u16
    u16* wbf1     = wbf0     + WBF_SZ;                     // WBF_SZ u16
    u16* ws_xcb   = (u16*)ws_Q;   // alias: dead before pass1 writes Q
    float* ws_par = ws_P;         // split-K partials (P/Q dead when used)

    // 0) one-shot convert: x, merge_w, all weights (both dirs)
    cvt_all_kernel<<<(N4_TOTAL + 255) / 256, 256, 0, stream>>>(
        x, merge_w, in_p[0], x_p[0], dt_w[0], out_p[0],
        in_p[1], x_p[1], dt_w[1], out_p[1],
        ws_xbf, wbf_mw,
        wbf0, wbf0 + O_XP, wbf0 + O_DT, wbf0 + O_OUT,
        wbf1, wbf1 + O_XP, wbf1 + O_DT, wbf1 + O_OUT);

    // 1) xz = x @ in_proj^T (both dirs; dir1 rows flipped)
    mfma_gemm<u16, float, 0, true, true, 1><<<dim3(64, 16, 2), 256, 0, stream>>>(
        ws_xbf, ws_xbf, DM, wbf0, wbf1, DM, nullptr, nullptr,
        ws_xz, ws_xz + (size_t)MM * 2 * DI, 2 * DI, MM, 2 * DI, DM);

    // 2) conv + silu (both dirs)
    conv_silu_kernel<<<(2 * MM * DI) / 256, 256, 0, stream>>>(
        ws_xz, conv_w[0], conv_w[1], conv_b[0], conv_b[1], ws_xc, ws_xcb);

    // 3) dbl = xc @ x_proj^T  (N=96, split-K4, both dirs)
    mfma_gemm<u16, float, 0, true, false, 4><<<dim3(2, 16, 8), 256, 0, stream>>>(
        ws_xcb, ws_xcb + (size_t)MM * DI, DI,
        wbf0 + O_XP, wbf1 + O_XP, DI, nullptr, nullptr,
        ws_par, ws_par + (size_t)4 * MM * NDBL, NDBL, MM, NDBL, DI);
    combine_dbl_kernel<<<(2 * MM * NDBL / 4) / 256, 256, 0, stream>>>(ws_par, ws_dbl);

    // 4) delta = softplus(dt @ dt_w^T + dt_b) -> bf16 (K=64, fp32 A, both dirs)
    mfma_gemm<float, u16, 1, true, false, 1><<<dim3(32, 16, 2), 256, 0, stream>>>(
        ws_dbl, ws_dbl + (size_t)MM * NDBL, NDBL,
        wbf0 + O_DT, wbf1 + O_DT, DR, dt_b[0], dt_b[1],
        ws_delta, ws_delta + (size_t)MM * DI, DI, MM, DI, DR);

    // 5) chunked scan (both dirs); pass3 writes y over delta
    {
        dim3 grid(NC, DI / 256, 2 * BSZ);
        scan_pass1<<<grid, 256, 0, stream>>>(ws_dbl, ws_xc, ws_delta,
                                             A_log[0], A_log[1], ws_P, ws_Q);
        scan_pass2<<<(2 * BSZ * DI * DS) / 256, 256, 0, stream>>>(ws_P, ws_Q, ws_H0);
        scan_pass3<<<grid, 256, 0, stream>>>(ws_dbl, ws_xc, ws_xz, ws_delta,
                                             A_log[0], A_log[1], Dp[0], Dp[1], ws_H0);
    }

    // 6) cat = y @ out_proj^T (split-K2, both dirs; dir1 rows flipped back)
    mfma_gemm<u16, float, 0, true, true, 2><<<dim3(16, 16, 4), 256, 0, stream>>>(
        ws_delta, ws_delta + (size_t)MM * DI, DI,
        wbf0 + O_OUT, wbf1 + O_OUT, DI, nullptr, nullptr,
        ws_par, ws_par + (size_t)2 * MM * DM, DM, MM, DM, DI);
    combine_cat_kernel<<<(2 * MM * DM / 4) / 256, 256, 0, stream>>>(ws_par, ws_cat);

    // 7) out = cat @ merge_w^T (split-K2, fp32 out)
    mfma_gemm<u16, float, 0, false, false, 2><<<dim3(16, 16, 2), 256, 0, stream>>>(
        ws_cat, ws_cat, 2 * DM, wbf_mw, wbf_mw, 2 * DM, nullptr, nullptr,
        ws_par, ws_par, DM, MM, DM, 2 * DM);
    combine_out_kernel<<<(MM * DM / 4) / 256, 256, 0, stream>>>(ws_par, out);
}

// Round 11
// 393.713 us; speedup vs baseline: 9.1385x; 1.0782x over previous
//
#include <hip/hip_runtime.h>
#include <math.h>

#define BSZ 2
#define SEQ 1024
#define DM  1024          // d_model
#define DI  2048          // d_inner
#define DS  16            // d_state
#define DC  4             // d_conv
#define DR  64            // dt_rank
#define NDBL 96           // DR + 2*DS
#define NC  32            // scan chunks
#define LC  32            // SEQ / NC
#define MM  (BSZ * SEQ)   // 2048 rows

typedef unsigned short u16;
typedef __bf16 bf16x8 __attribute__((ext_vector_type(8)));
typedef float  f32x4  __attribute__((ext_vector_type(4)));

// ---- segment sizes (float4 units) and weight-block offsets (u16 units) ----
constexpr int N4_X   = MM * DM / 4;          //   524,288
constexpr int N4_MW  = DM * 2 * DM / 4;      //   524,288
constexpr int N4_IN  = 2 * DI * DM / 4;      // 1,048,576
constexpr int N4_XP  = NDBL * DI / 4;        //    49,152
constexpr int N4_DT  = DI * DR / 4;          //    32,768
constexpr int N4_OUT = DM * DI / 4;          //   524,288
constexpr int N4_TOTAL = N4_X + N4_MW + 2 * (N4_IN + N4_XP + N4_DT + N4_OUT);
constexpr size_t O_XP  = (size_t)2 * DI * DM;            // 4,194,304
constexpr size_t O_DT  = O_XP + (size_t)NDBL * DI;       // 4,390,912
constexpr size_t O_OUT = O_DT + (size_t)DI * DR;         // 4,521,984
constexpr size_t WBF_SZ = O_OUT + (size_t)DM * DI;       // 6,619,136 u16 per dir

__device__ __forceinline__ u16 f2b(float f) {
    unsigned int u = __float_as_uint(f);
    unsigned int r = (u + 0x7fffu + ((u >> 16) & 1u)) >> 16;
    return (u16)r;
}
__device__ __forceinline__ float b2f(u16 h) {
    return __uint_as_float(((unsigned int)h) << 16);
}

__device__ __forceinline__ void stf(float* p, size_t i, float v) { p[i] = v; }
__device__ __forceinline__ void stf(u16* p, size_t i, float v)   { p[i] = f2b(v); }

// ---- fast transcendentals ----
__device__ __forceinline__ float fexp(float x)  { return __expf(x); }
__device__ __forceinline__ float frcp(float x)  { return __builtin_amdgcn_rcpf(x); }
__device__ __forceinline__ float silu_fast(float x) {
    return x * frcp(1.f + fexp(-x));
}
__device__ __forceinline__ float softplus_fast(float x) {
    return (x > 15.f) ? x : __logf(1.f + fexp(x));
}

// ---- async global->LDS, 16B/lane; dest = wave-uniform base + lane*16 ----
__device__ __forceinline__ void async16(const u16* g, u16* l) {
    __builtin_amdgcn_global_load_lds(
        (const __attribute__((address_space(1))) void*)g,
        (__attribute__((address_space(3))) void*)l, 16, 0, 0);
}

// XOR-swizzle: 16B-slot for (row, 8-elem chunk j) — 2-way bank aliasing only.
__device__ __forceinline__ int lds_slot(int row, int j) {
    return row * 4 + ((j + (row >> 1)) & 3);
}

// ---- staging helper for fp32 A: 8 floats -> 8 bf16 at LDS slot ----
__device__ __forceinline__ void stage8f(const float* p, u16* d) {
    float4 v0 = *(const float4*)p;
    float4 v1 = *(const float4*)(p + 4);
    ushort4 a; a.x = f2b(v0.x); a.y = f2b(v0.y); a.z = f2b(v0.z); a.w = f2b(v0.w);
    ushort4 b; b.x = f2b(v1.x); b.y = f2b(v1.y); b.z = f2b(v1.z); b.w = f2b(v1.w);
    *(ushort4*)d = a;
    *(ushort4*)(d + 4) = b;
}

// ---- one-shot fp32->bf16 convert of x, merge_w, and both dirs' weights ----
__global__ __launch_bounds__(256) void cvt_all_kernel(
    const float* __restrict__ s0, const float* __restrict__ s1,
    const float* __restrict__ s2, const float* __restrict__ s3,
    const float* __restrict__ s4, const float* __restrict__ s5,
    const float* __restrict__ s6, const float* __restrict__ s7,
    const float* __restrict__ s8, const float* __restrict__ s9,
    u16* __restrict__ d0, u16* __restrict__ d1, u16* __restrict__ d2,
    u16* __restrict__ d3, u16* __restrict__ d4, u16* __restrict__ d5,
    u16* __restrict__ d6, u16* __restrict__ d7, u16* __restrict__ d8,
    u16* __restrict__ d9)
{
    int i = blockIdx.x * 256 + threadIdx.x;
    const float* s; u16* d;
    if (i < N4_X) { s = s0; d = d0; }                    // x
    else if ((i -= N4_X) < N4_MW) { s = s1; d = d1; }    // merge_w
    else if ((i -= N4_MW) < N4_IN) { s = s2; d = d2; }   // in0
    else if ((i -= N4_IN) < N4_XP) { s = s3; d = d3; }   // xp0
    else if ((i -= N4_XP) < N4_DT) { s = s4; d = d4; }   // dt0
    else if ((i -= N4_DT) < N4_OUT) { s = s5; d = d5; }  // out0
    else if ((i -= N4_OUT) < N4_IN) { s = s6; d = d6; }  // in1
    else if ((i -= N4_IN) < N4_XP) { s = s7; d = d7; }   // xp1
    else if ((i -= N4_XP) < N4_DT) { s = s8; d = d8; }   // dt1
    else if ((i -= N4_DT) < N4_OUT) { s = s9; d = d9; }  // out1
    else return;
    float4 v = ((const float4*)s)[i];
    ushort4 o; o.x = f2b(v.x); o.y = f2b(v.y); o.z = f2b(v.z); o.w = f2b(v.w);
    ((ushort4*)d)[i] = o;
}

// ---------------- dual-direction MFMA GEMM --------------------------------
// C[M,N] = act(A[M,K] @ W[N,K]^T + bias). Tile 128(M) x BN(N), BK=32,
// 256 threads = 4 waves in 2x2 (wave tile 64 x BN/2).
// blockIdx.z = dir*NSPLIT + split (DUAL) or split (non-dual).
// NSPLIT>1: TC must be float; C = plane base + split*M*ldc (fp32 partials).
// FLIP1: dir-1 output rows are flipped within each batch's SEQ rows.
template <typename TA, typename TC, int ACT, bool DUAL, bool FLIP1, int NSPLIT, int BN>
__global__ __launch_bounds__(256) void mfma_gemm(
    const TA* __restrict__ A0, const TA* __restrict__ A1, int lda,
    const u16* __restrict__ W0, const u16* __restrict__ W1, int ldw,
    const float* __restrict__ bias0, const float* __restrict__ bias1,
    TC* __restrict__ C0, TC* __restrict__ C1, int ldc,
    int M, int N, int K)
{
    constexpr int NF = BN / 32;          // n-fragments per wave (2 or 4)
    __shared__ u16 As[128 * 32];
    __shared__ u16 Ws[BN * 32];

    const int z = blockIdx.z;
    const int dir = DUAL ? (z / NSPLIT) : 0;
    const int split = z % NSPLIT;
    const TA* A = dir ? A1 : A0;
    const u16* W = dir ? W1 : W0;
    const float* bias = dir ? bias1 : bias0;
    TC* C = dir ? C1 : C0;
    if (NSPLIT > 1) C += (size_t)split * M * ldc;
    const int kseg = K / NSPLIT;
    const int kbeg = split * kseg, kend = kbeg + kseg;

    const int t = threadIdx.x;
    const int wave = t >> 6;
    const int lane = t & 63;
    const int wm = (wave & 1) * 64;
    const int wn = (wave >> 1) * (BN / 2);
    const int fm = lane & 15;
    const int q  = lane >> 4;
    const int m0 = blockIdx.y * 128;
    const int n0 = blockIdx.x * BN;

    f32x4 acc[4][NF] = {};

    for (int k0 = kbeg; k0 < kend; k0 += 32) {
        if constexpr (__is_same(TA, u16)) {
            #pragma unroll
            for (int p = 0; p < 2; p++) {
                int i = p * 256 + wave * 64 + lane;
                int r = i >> 2;
                int j = ((i & 3) - (r >> 1)) & 3;
                async16(A + (size_t)(m0 + r) * lda + k0 + j * 8,
                        &As[(size_t)(p * 256 + wave * 64) * 8]);
            }
        } else {
            #pragma unroll
            for (int p = 0; p < 2; p++) {
                int i = p * 256 + t;
                int r = i >> 2;
                int j = ((i & 3) - (r >> 1)) & 3;
                stage8f(A + (size_t)(m0 + r) * lda + k0 + j * 8, &As[(size_t)i * 8]);
            }
        }
        #pragma unroll
        for (int p = 0; p < BN / 64; p++) {
            int i = p * 256 + wave * 64 + lane;
            int r = i >> 2;
            int j = ((i & 3) - (r >> 1)) & 3;
            int gr = n0 + r;
            if (gr >= N) gr = N - 1;   // clamp (junk discarded at store)
            async16(W + (size_t)gr * ldw + k0 + j * 8,
                    &Ws[(size_t)(p * 256 + wave * 64) * 8]);
        }
        __syncthreads();

        bf16x8 af[4], wf[NF];
        #pragma unroll
        for (int mi = 0; mi < 4; mi++)
            af[mi] = *(const bf16x8*)&As[(size_t)lds_slot(wm + mi * 16 + fm, q) * 8];
        #pragma unroll
        for (int ni = 0; ni < NF; ni++)
            wf[ni] = *(const bf16x8*)&Ws[(size_t)lds_slot(wn + ni * 16 + fm, q) * 8];
        #pragma unroll
        for (int mi = 0; mi < 4; mi++)
            #pragma unroll
            for (int ni = 0; ni < NF; ni++)
                acc[mi][ni] = __builtin_amdgcn_mfma_f32_16x16x32_bf16(
                    af[mi], wf[ni], acc[mi][ni], 0, 0, 0);
        __syncthreads();
    }

    // C/D layout: col = lane&15, row = (lane>>4)*4 + reg
    const int rb = q * 4;
    const int cc = fm;
    #pragma unroll
    for (int mi = 0; mi < 4; mi++) {
        #pragma unroll
        for (int r = 0; r < 4; r++) {
            int gm = m0 + wm + mi * 16 + rb + r;
            int om = gm;
            if (FLIP1 && dir == 1) {
                int bb = gm / SEQ, l = gm % SEQ;
                om = bb * SEQ + (SEQ - 1 - l);
            }
            #pragma unroll
            for (int ni = 0; ni < NF; ni++) {
                int gn = n0 + wn + ni * 16 + cc;
                if (gn < N) {
                    float v = acc[mi][ni][r];
                    if (ACT == 1) v = softplus_fast(v + bias[gn]);
                    stf(C, (size_t)om * ldc + gn, v);
                }
            }
        }
    }
}

// ---- split-K combines ----
__global__ __launch_bounds__(256) void combine_dbl_kernel(
    const float* __restrict__ par, float* __restrict__ dbl)
{
    int i4 = blockIdx.x * 256 + threadIdx.x;   // [0, 2*MM*NDBL/4)
    const int per = (MM * NDBL) / 4;           // 49152
    int dir = (i4 >= per) ? 1 : 0;
    int j4 = i4 - dir * per;
    const float* p = par + (size_t)dir * 4 * MM * NDBL;
    f32x4 s = {0.f, 0.f, 0.f, 0.f};
    #pragma unroll
    for (int k = 0; k < 4; k++)
        s += *(const f32x4*)&p[(size_t)k * MM * NDBL + (size_t)j4 * 4];
    *(f32x4*)&dbl[(size_t)dir * MM * NDBL + (size_t)j4 * 4] = s;
}

__global__ __launch_bounds__(256) void combine_cat_kernel(
    const float* __restrict__ par, u16* __restrict__ cat)
{
    int i4 = blockIdx.x * 256 + threadIdx.x;   // [0, 2*MM*DM/4)
    const int per = (MM * DM) / 4;             // 524288
    int dir = (i4 >= per) ? 1 : 0;
    int j4 = i4 - dir * per;
    const float* p0 = par + (size_t)dir * 2 * MM * DM;
    const float* p1 = p0 + (size_t)MM * DM;
    f32x4 a = *(const f32x4*)&p0[(size_t)j4 * 4];
    f32x4 b = *(const f32x4*)&p1[(size_t)j4 * 4];
    int m = j4 >> 8;           // DM/4 = 256 float4 per row
    int n4 = j4 & 255;
    ushort4 o;
    o.x = f2b(a[0] + b[0]); o.y = f2b(a[1] + b[1]);
    o.z = f2b(a[2] + b[2]); o.w = f2b(a[3] + b[3]);
    *(ushort4*)&cat[(size_t)m * 2 * DM + dir * DM + n4 * 4] = o;
}

__global__ __launch_bounds__(256) void combine_out_kernel(
    const float* __restrict__ p0, float* __restrict__ out)
{
    int i4 = blockIdx.x * 256 + threadIdx.x;   // [0, MM*DM/4)
    const float* p1 = p0 + (size_t)MM * DM;
    f32x4 a = *(const f32x4*)&p0[(size_t)i4 * 4];
    f32x4 b = *(const f32x4*)&p1[(size_t)i4 * 4];
    *(f32x4*)&out[(size_t)i4 * 4] = a + b;
}

// ---- conv + silu, both dirs, 4 channels/thread; writes bf16 xcb only ----
__global__ __launch_bounds__(256) void conv_silu_kernel(
    const float* __restrict__ xz,
    const float* __restrict__ cw0, const float* __restrict__ cw1,
    const float* __restrict__ cb0, const float* __restrict__ cb1,
    u16* __restrict__ xcb)
{
    int i4 = blockIdx.x * 256 + threadIdx.x;    // [0, 2*MM*DI/4)
    const int per = MM * DI / 4;
    int dir = (i4 >= per) ? 1 : 0;
    int rem = i4 - dir * per;
    int e4 = rem & (DI / 4 - 1);
    int bl = rem / (DI / 4);
    int l = bl & (SEQ - 1);
    int e = e4 * 4;
    const float* xz_d = xz + (size_t)dir * MM * 2 * DI;
    const float* cw = dir ? cw1 : cw0;
    const float* cb = dir ? cb1 : cb0;
    f32x4 cwv[4];
    #pragma unroll
    for (int i = 0; i < 4; i++) cwv[i] = *(const f32x4*)&cw[(e + i) * DC];
    f32x4 acc = *(const f32x4*)&cb[e];
    #pragma unroll
    for (int k = 0; k < DC; k++) {
        int ll = l + k - (DC - 1);
        if (ll >= 0) {
            f32x4 xv = *(const f32x4*)&xz_d[(size_t)(bl - l + ll) * (2 * DI) + e];
            #pragma unroll
            for (int i = 0; i < 4; i++) acc[i] += cwv[i][k] * xv[i];
        }
    }
    ushort4 o;
    #pragma unroll
    for (int i = 0; i < 4; i++) {
        float s = silu_fast(acc[i]);
        ((u16*)&o)[i] = f2b(s);
    }
    ((ushort4*)xcb)[(size_t)dir * per + rem] = o;
}

// ---- Chunked scan, both dirs, n-in-registers; xc is bf16 now ----
// grid (NC, DI/256, 2*BSZ); z: dir = z>>1, b = z&1.
__global__ __launch_bounds__(256) void scan_pass1(
    const float* __restrict__ dbl,
    const u16*  __restrict__ xc,
    const u16*  __restrict__ delta,
    const float* __restrict__ Alog0, const float* __restrict__ Alog1,
    float* __restrict__ Pout, float* __restrict__ Qout)
{
    __shared__ float sB[LC][16];
    const int t = threadIdx.x;
    const int c = blockIdx.x;
    const int dir = blockIdx.z >> 1;
    const int b = blockIdx.z & 1;
    const int e = blockIdx.y * 256 + t;
    const int row0 = b * SEQ + c * LC;
    const float* dbl_d = dbl + (size_t)dir * MM * NDBL;
    const u16* xc_d = xc + (size_t)dir * MM * DI;
    const u16* delta_d = delta + (size_t)dir * MM * DI;
    const float* A_log = dir ? Alog1 : Alog0;
    float* P_d = Pout + (size_t)dir * BSZ * NC * DI * DS;
    float* Q_d = Qout + (size_t)dir * BSZ * NC * DI * DS;

    if (t < LC * 4) {
        int row = t >> 2, col = (t & 3) * 4;
        *(f32x4*)&sB[row][col] =
            *(const f32x4*)&dbl_d[(size_t)(row0 + row) * NDBL + DR + col];
    }

    f32x4 Aen[4], P[4], Q[4];
    #pragma unroll
    for (int g = 0; g < 4; g++) {
        f32x4 a = *(const f32x4*)&A_log[(size_t)e * DS + g * 4];
        #pragma unroll
        for (int j = 0; j < 4; j++) Aen[g][j] = -fexp(a[j]);
        P[g] = f32x4{1.f, 1.f, 1.f, 1.f};
        Q[g] = f32x4{0.f, 0.f, 0.f, 0.f};
    }
    __syncthreads();

    float dv = b2f(delta_d[(size_t)row0 * DI + e]);
    float xv = b2f(xc_d[(size_t)row0 * DI + e]);
    for (int i = 0; i < LC; i++) {
        int ip = (i + 1 < LC) ? (i + 1) : (LC - 1);
        float dvn = b2f(delta_d[(size_t)(row0 + ip) * DI + e]);
        float xvn = b2f(xc_d[(size_t)(row0 + ip) * DI + e]);
        float du = dv * xv;
        #pragma unroll
        for (int g = 0; g < 4; g++) {
            f32x4 Bv = *(const f32x4*)&sB[i][g * 4];
            #pragma unroll
            for (int j = 0; j < 4; j++) {
                float dA = fexp(dv * Aen[g][j]);
                P[g][j] *= dA;
                Q[g][j] = dA * Q[g][j] + du * Bv[j];
            }
        }
        dv = dvn; xv = xvn;
    }
    size_t base = ((size_t)(b * NC + c) * DI + e) * DS;
    #pragma unroll
    for (int g = 0; g < 4; g++) {
        *(f32x4*)&P_d[base + g * 4] = P[g];
        *(f32x4*)&Q_d[base + g * 4] = Q[g];
    }
}

__global__ __launch_bounds__(256) void scan_pass2(
    const float* __restrict__ P, const float* __restrict__ Q,
    float* __restrict__ H0)
{
    const int gid = blockIdx.x * 256 + threadIdx.x;  // [0, 2*BSZ*DI*DS)
    const int dir = gid >> 16;
    const int loc = gid & 65535;
    const int b = loc >> 15;
    const int en = loc & (DI * DS - 1);
    size_t doff = (size_t)dir * BSZ * NC * DI * DS;
    float h = 0.f;
    for (int c = 0; c < NC; c++) {
        size_t idx = doff + ((size_t)(b * NC + c) * DI * DS) + en;
        H0[idx] = h;
        h = P[idx] * h + Q[idx];
    }
}

// pass3: replay chunk; writes gated y IN-PLACE over delta
__global__ __launch_bounds__(256) void scan_pass3(
    const float* __restrict__ dbl,
    const u16*  __restrict__ xc,
    const float* __restrict__ xz,
    u16* delta_y,
    const float* __restrict__ Alog0, const float* __restrict__ Alog1,
    const float* __restrict__ Dp0, const float* __restrict__ Dp1,
    const float* __restrict__ H0)
{
    __shared__ float sBC[LC][32];
    const int t = threadIdx.x;
    const int c = blockIdx.x;
    const int dir = blockIdx.z >> 1;
    const int b = blockIdx.z & 1;
    const int e = blockIdx.y * 256 + t;
    const int row0 = b * SEQ + c * LC;
    const float* dbl_d = dbl + (size_t)dir * MM * NDBL;
    const u16* xc_d = xc + (size_t)dir * MM * DI;
    const float* xz_d = xz + (size_t)dir * MM * 2 * DI;
    u16* dy_d = delta_y + (size_t)dir * MM * DI;
    const float* A_log = dir ? Alog1 : Alog0;
    const float* Dp = dir ? Dp1 : Dp0;
    const float* H0_d = H0 + (size_t)dir * BSZ * NC * DI * DS;

    {
        int row = t >> 3, col = (t & 7) * 4;
        *(f32x4*)&sBC[row][col] =
            *(const f32x4*)&dbl_d[(size_t)(row0 + row) * NDBL + DR + col];
    }

    f32x4 Aen[4], h[4];
    size_t base = ((size_t)(b * NC + c) * DI + e) * DS;
    #pragma unroll
    for (int g = 0; g < 4; g++) {
        f32x4 a = *(const f32x4*)&A_log[(size_t)e * DS + g * 4];
        #pragma unroll
        for (int j = 0; j < 4; j++) Aen[g][j] = -fexp(a[j]);
        h[g] = *(const f32x4*)&H0_d[base + g * 4];
    }
    const float Dv = Dp[e];
    __syncthreads();

    float dv = b2f(dy_d[(size_t)row0 * DI + e]);
    float xv = b2f(xc_d[(size_t)row0 * DI + e]);
    float zv = xz_d[(size_t)row0 * (2 * DI) + DI + e];
    for (int i = 0; i < LC; i++) {
        int ip = (i + 1 < LC) ? (i + 1) : (LC - 1);
        float dvn = b2f(dy_d[(size_t)(row0 + ip) * DI + e]);
        float xvn = b2f(xc_d[(size_t)(row0 + ip) * DI + e]);
        float zvn = xz_d[(size_t)(row0 + ip) * (2 * DI) + DI + e];
        float du = dv * xv;
        f32x4 pv = {0.f, 0.f, 0.f, 0.f};
        #pragma unroll
        for (int g = 0; g < 4; g++) {
            f32x4 Bv = *(const f32x4*)&sBC[i][g * 4];
            f32x4 Cv = *(const f32x4*)&sBC[i][16 + g * 4];
            #pragma unroll
            for (int j = 0; j < 4; j++) {
                float dA = fexp(dv * Aen[g][j]);
                h[g][j] = dA * h[g][j] + du * Bv[j];
                pv[j] += h[g][j] * Cv[j];
            }
        }
        float p = pv[0] + pv[1] + pv[2] + pv[3];
        float y = (p + xv * Dv) * silu_fast(zv);
        dy_d[(size_t)(row0 + i) * DI + e] = f2b(y);
        dv = dvn; xv = xvn; zv = zvn;
    }
}

extern "C" void kernel_launch(void* const* d_in, const int* in_sizes, int n_in,
                              void* d_out, int out_size, void* d_ws, size_t ws_size,
                              hipStream_t stream)
{
    const float* x = (const float*)d_in[0];
    const float* in_p[2]  = {(const float*)d_in[1],  (const float*)d_in[10]};
    const float* conv_w[2]= {(const float*)d_in[2],  (const float*)d_in[11]};
    const float* conv_b[2]= {(const float*)d_in[3],  (const float*)d_in[12]};
    const float* x_p[2]   = {(const float*)d_in[4],  (const float*)d_in[13]};
    const float* dt_w[2]  = {(const float*)d_in[5],  (const float*)d_in[14]};
    const float* dt_b[2]  = {(const float*)d_in[6],  (const float*)d_in[15]};
    const float* A_log[2] = {(const float*)d_in[7],  (const float*)d_in[16]};
    const float* Dp[2]    = {(const float*)d_in[8],  (const float*)d_in[17]};
    const float* out_p[2] = {(const float*)d_in[9],  (const float*)d_in[18]};
    const float* merge_w  = (const float*)d_in[19];
    float* out = (float*)d_out;

    // ---- workspace layout (element units) ----
    float* ws = (float*)d_ws;
    float* ws_xz  = ws;                                    // 2 * MM*2DI f
    float* ws_dbl = ws_xz  + (size_t)2 * MM * 2 * DI;      // 2 * MM*NDBL f
    float* ws_P   = ws_dbl + (size_t)2 * MM * NDBL;        // 2 * BSZ*NC*DI*DS f
    float* ws_Q   = ws_P   + (size_t)2 * BSZ * NC * DI * DS;
    float* ws_H0  = ws_Q   + (size_t)2 * BSZ * NC * DI * DS;
    u16* ws_delta = (u16*)(ws_H0 + (size_t)2 * BSZ * NC * DI * DS); // 2*MM*DI u16
    u16* ws_xcb   = ws_delta + (size_t)2 * MM * DI;        // 2*MM*DI u16
    u16* ws_cat   = ws_xcb   + (size_t)2 * MM * DI;        // MM*2DM u16
    u16* ws_xbf   = ws_cat   + (size_t)MM * 2 * DM;        // MM*DM u16
    u16* wbf_mw   = ws_xbf   + (size_t)MM * DM;            // DM*2DM u16
    u16* wbf0     = wbf_mw   + (size_t)DM * 2 * DM;        // WBF_SZ u16
    u16* wbf1     = wbf0     + WBF_SZ;                     // WBF_SZ u16
    float* ws_par = ws_P;         // split-K partials (P/Q dead when used)

    // 0) one-shot convert: x, merge_w, all weights (both dirs)
    cvt_all_kernel<<<(N4_TOTAL + 255) / 256, 256, 0, stream>>>(
        x, merge_w, in_p[0], x_p[0], dt_w[0], out_p[0],
        in_p[1], x_p[1], dt_w[1], out_p[1],
        ws_xbf, wbf_mw,
        wbf0, wbf0 + O_XP, wbf0 + O_DT, wbf0 + O_OUT,
        wbf1, wbf1 + O_XP, wbf1 + O_DT, wbf1 + O_OUT);

    // 1) xz = x @ in_proj^T (both dirs; dir1 rows flipped) — 128x128 tile
    mfma_gemm<u16, float, 0, true, true, 1, 128><<<dim3(32, 16, 2), 256, 0, stream>>>(
        ws_xbf, ws_xbf, DM, wbf0, wbf1, DM, nullptr, nullptr,
        ws_xz, ws_xz + (size_t)MM * 2 * DI, 2 * DI, MM, 2 * DI, DM);

    // 2) conv + silu (both dirs, 4-wide, bf16 out)
    conv_silu_kernel<<<(2 * MM * DI / 4) / 256, 256, 0, stream>>>(
        ws_xz, conv_w[0], conv_w[1], conv_b[0], conv_b[1], ws_xcb);

    // 3) dbl = xc @ x_proj^T  (N=96, split-K4, both dirs)
    mfma_gemm<u16, float, 0, true, false, 4, 64><<<dim3(2, 16, 8), 256, 0, stream>>>(
        ws_xcb, ws_xcb + (size_t)MM * DI, DI,
        wbf0 + O_XP, wbf1 + O_XP, DI, nullptr, nullptr,
        ws_par, ws_par + (size_t)4 * MM * NDBL, NDBL, MM, NDBL, DI);
    combine_dbl_kernel<<<(2 * MM * NDBL / 4) / 256, 256, 0, stream>>>(ws_par, ws_dbl);

    // 4) delta = softplus(dt @ dt_w^T + dt_b) -> bf16 (K=64, fp32 A, both dirs)
    mfma_gemm<float, u16, 1, true, false, 1, 64><<<dim3(32, 16, 2), 256, 0, stream>>>(
        ws_dbl, ws_dbl + (size_t)MM * NDBL, NDBL,
        wbf0 + O_DT, wbf1 + O_DT, DR, dt_b[0], dt_b[1],
        ws_delta, ws_delta + (size_t)MM * DI, DI, MM, DI, DR);

    // 5) chunked scan (both dirs); pass3 writes y over delta
    {
        dim3 grid(NC, DI / 256, 2 * BSZ);
        scan_pass1<<<grid, 256, 0, stream>>>(ws_dbl, ws_xcb, ws_delta,
                                             A_log[0], A_log[1], ws_P, ws_Q);
        scan_pass2<<<(2 * BSZ * DI * DS) / 256, 256, 0, stream>>>(ws_P, ws_Q, ws_H0);
        scan_pass3<<<grid, 256, 0, stream>>>(ws_dbl, ws_xcb, ws_xz, ws_delta,
                                             A_log[0], A_log[1], Dp[0], Dp[1], ws_H0);
    }

    // 6) cat = y @ out_proj^T (split-K2, both dirs; dir1 rows flipped back)
    mfma_gemm<u16, float, 0, true, true, 2, 64><<<dim3(16, 16, 4), 256, 0, stream>>>(
        ws_delta, ws_delta + (size_t)MM * DI, DI,
        wbf0 + O_OUT, wbf1 + O_OUT, DI, nullptr, nullptr,
        ws_par, ws_par + (size_t)2 * MM * DM, DM, MM, DM, DI);
    combine_cat_kernel<<<(2 * MM * DM / 4) / 256, 256, 0, stream>>>(ws_par, ws_cat);

    // 7) out = cat @ merge_w^T (split-K2, fp32 out)
    mfma_gemm<u16, float, 0, false, false, 2, 64><<<dim3(16, 16, 2), 256, 0, stream>>>(
        ws_cat, ws_cat, 2 * DM, wbf_mw, wbf_mw, 2 * DM, nullptr, nullptr,
        ws_par, ws_par, DM, MM, DM, 2 * DM);
    combine_out_kernel<<<(MM * DM / 4) / 256, 256, 0, stream>>>(ws_par, out);
}